// Round 2
// baseline (196.533 us; speedup 1.0000x reference)
//
#include <hip/hip_runtime.h>

// GraphCodeBertCPDP forward on MI355X (gfx950).
// Inputs/outputs are FLOAT32 (per reference). GEMMs run in bf16 MFMA with f32
// accumulation (tolerances are bf16-grade generous); all small ops stay f32.
// Pipeline:
//   0. cvt: line_emb f32 -> bf16 (Abf); cvt-transpose W1,W2 -> bf16 W1t,W2t
//   1. GEMM1: H = Abf[32768,768] @ W1t^T -> f32
//   2. stencil1: G1 = bf16(relu(gcn_stencil(H) + b1))
//   3. GEMM2: H = G1 @ W2t^T -> f32   (reuses H buffer)
//   4. stencil2: hbuf = gcn_stencil(H) + b2 -> f32  (overlays dead Abf)
//   5. attn_pool per file -> h_file, att_weights
//   6. head per file -> z_shared/z_private/logits_cls/domain_logits
//   7. ortho = ||l2n(zs)^T @ l2n(zp)||_F
// Output layout (f32), concatenated:
//   [0:512) logits_cls | [512:66048) h_file | [66048:98816) z_shared
//   [98816:131584) z_private | [131584:164352) att_weights
//   [164352:164864) domain_logits | [164864] ortho

typedef __attribute__((ext_vector_type(8))) short bf16x8;
typedef __attribute__((ext_vector_type(4))) float f32x4;

__device__ __forceinline__ unsigned short f2bf(float f) {
  union { float f; unsigned int i; } v; v.f = f;
  unsigned int r = v.i + 0x7FFFu + ((v.i >> 16) & 1u);
  return (unsigned short)(r >> 16);
}

// ---------------- f32 -> bf16 bulk convert (vectorized) -------------------
__global__ __launch_bounds__(256) void cvt_bf16(const float* __restrict__ src,
                                                unsigned short* __restrict__ dst,
                                                long n4) {
  long i = (long)blockIdx.x * 256 + threadIdx.x;
  if (i >= n4) return;
  f32x4 v = *(const f32x4*)&src[i * 4];
  unsigned short o[4];
#pragma unroll
  for (int j = 0; j < 4; ++j) o[j] = f2bf(v[j]);
  *(__attribute__((ext_vector_type(4))) short*)&dst[i * 4] =
      *(__attribute__((ext_vector_type(4))) short*)o;
}

// ------------- convert + transpose: dst[C][R] = bf16(src[R][C]) -----------
__global__ void cvt_transpose(const float* __restrict__ src,
                              unsigned short* __restrict__ dst, int R, int C) {
  int idx = blockIdx.x * 256 + threadIdx.x;
  if (idx >= R * C) return;
  int cc = idx / R, rr = idx - cc * R;
  dst[idx] = f2bf(src[rr * C + cc]);
}

// ---------------- MFMA GEMM: C[M,N] f32 = A[M,K]bf16 @ Bt[N,K]bf16^T ------
// 128x128 tile, BK=64, 4 waves (2x2 of 64x64), global_load_lds staging (m97).
__global__ __launch_bounds__(256) void gemm_bt(const unsigned short* __restrict__ A,
                                               const unsigned short* __restrict__ Bt,
                                               float* __restrict__ C,
                                               int M, int N, int K) {
  __shared__ __align__(16) unsigned short sA[128 * 64];
  __shared__ __align__(16) unsigned short sB[128 * 64];
  const int t = threadIdx.x;
  const int wave = t >> 6, lane = t & 63;
  const int wr = wave >> 1, wc = wave & 1;
  const long rowA = (long)blockIdx.x * 128;
  const long rowB = (long)blockIdx.y * 128;

  f32x4 acc[4][4];
#pragma unroll
  for (int m = 0; m < 4; ++m)
#pragma unroll
    for (int n = 0; n < 4; ++n) acc[m][n] = (f32x4)0.0f;

  const int r0 = lane >> 3;        // 0..7 row within 8-row group
  const int k0 = (lane & 7) * 8;   // 0..56

  for (int kt = 0; kt < K; kt += 64) {
#pragma unroll
    for (int l = 0; l < 4; ++l) {
      int li = wave * 4 + l;  // wave-uniform 0..15; 8 rows x 64 cols each
      const unsigned short* gA = A + (rowA + li * 8 + r0) * (long)K + kt + k0;
      const unsigned short* gB = Bt + (rowB + li * 8 + r0) * (long)K + kt + k0;
      __builtin_amdgcn_global_load_lds(
          (const __attribute__((address_space(1))) unsigned int*)gA,
          (__attribute__((address_space(3))) unsigned int*)&sA[li * 512], 16, 0, 0);
      __builtin_amdgcn_global_load_lds(
          (const __attribute__((address_space(1))) unsigned int*)gB,
          (__attribute__((address_space(3))) unsigned int*)&sB[li * 512], 16, 0, 0);
    }
    __syncthreads();
#pragma unroll
    for (int kk = 0; kk < 64; kk += 32) {
      const int kb = kk + (lane >> 4) * 8;
      bf16x8 af[4], bfr[4];
#pragma unroll
      for (int m = 0; m < 4; ++m)
        af[m] = *(const bf16x8*)&sA[(wr * 64 + m * 16 + (lane & 15)) * 64 + kb];
#pragma unroll
      for (int n = 0; n < 4; ++n)
        bfr[n] = *(const bf16x8*)&sB[(wc * 64 + n * 16 + (lane & 15)) * 64 + kb];
#pragma unroll
      for (int m = 0; m < 4; ++m)
#pragma unroll
        for (int n = 0; n < 4; ++n)
          acc[m][n] = __builtin_amdgcn_mfma_f32_16x16x32_bf16(af[m], bfr[n], acc[m][n], 0, 0, 0);
    }
    __syncthreads();
  }
  // epilogue: C/D layout col=lane&15, row=(lane>>4)*4+j  (m89-verified)
#pragma unroll
  for (int m = 0; m < 4; ++m)
#pragma unroll
    for (int n = 0; n < 4; ++n) {
      long r = rowA + wr * 64 + m * 16 + (lane >> 4) * 4;
      long c = rowB + wc * 64 + n * 16 + (lane & 15);
#pragma unroll
      for (int j = 0; j < 4; ++j) C[(r + j) * N + c] = acc[m][n][j];
    }
}

// ---------------- GCN normalize stencil (+bias, optional relu) -----------
// One block = one line (256 channels). out[i] = sum_{o=-2..2} nrm(p,o)*Hin[i+o] + b
__global__ __launch_bounds__(256) void gcn_stencil(const float* __restrict__ Hin,
                                                   const float* __restrict__ bias,
                                                   unsigned short* __restrict__ outBf,
                                                   float* __restrict__ outF,
                                                   int mode /*0: relu->bf16, 1: ->f32*/) {
  const long i = blockIdx.x;        // line index 0..32767
  const int c = threadIdx.x;        // channel
  const int p = (int)(i & 127);     // position within file
  const int dp = 5 - (p < 2 ? 2 - p : 0) - (p > 125 ? p - 125 : 0);
  float acc = 0.f;
#pragma unroll
  for (int o = -2; o <= 2; ++o) {
    int q = p + o;
    if (q < 0 || q > 127) continue;
    int dq = 5 - (q < 2 ? 2 - q : 0) - (q > 125 ? q - 125 : 0);
    float w = 1.0f / sqrtf((float)(dp * dq));
    acc += w * Hin[(i + o) * 256 + c];
  }
  acc += bias[c];
  long idx = i * 256 + c;
  if (mode == 0) {
    acc = fmaxf(acc, 0.f);
    outBf[idx] = f2bf(acc);
  } else {
    outF[idx] = acc;
  }
}

// ---------------- per-file attention pooling ------------------------------
__global__ __launch_bounds__(256) void attn_pool(const float* __restrict__ h,
                                                 const float* __restrict__ attn_w,
                                                 const float* __restrict__ attn_b,
                                                 float* __restrict__ hf_ws,
                                                 float* __restrict__ out) {
  const int f = blockIdx.x, t = threadIdx.x;
  __shared__ float aw[256];
  __shared__ float lg[128];
  __shared__ float red[128];
  aw[t] = attn_w[t];
  __syncthreads();
  const float* hb = h + (long)f * 128 * 256;
  if (t < 128) {
    float a = 0.f;
    for (int c = 0; c < 256; ++c) a += hb[t * 256 + c] * aw[c];
    lg[t] = a + attn_b[0];
    red[t] = lg[t];
  }
  __syncthreads();
  for (int s = 64; s > 0; s >>= 1) {
    if (t < s) red[t] = fmaxf(red[t], red[t + s]);
    __syncthreads();
  }
  float mx = red[0];
  __syncthreads();
  if (t < 128) { lg[t] = expf(lg[t] - mx); red[t] = lg[t]; }
  __syncthreads();
  for (int s = 64; s > 0; s >>= 1) {
    if (t < s) red[t] += red[t + s];
    __syncthreads();
  }
  float dn = red[0];
  __syncthreads();
  if (t < 128) {
    float w = lg[t] / dn;
    lg[t] = w;
    out[131584 + f * 128 + t] = w;
  }
  __syncthreads();
  float acc = 0.f;
  for (int r = 0; r < 128; ++r) acc += lg[r] * hb[r * 256 + t];
  hf_ws[f * 256 + t] = acc;
  out[512 + f * 256 + t] = acc;
}

// ---------------- per-file heads: z_shared/z_private/cls/domain -----------
__global__ __launch_bounds__(128) void head_kernel(const float* __restrict__ hf_ws,
    const float* __restrict__ Ws, const float* __restrict__ bs,
    const float* __restrict__ Wp, const float* __restrict__ bp,
    const float* __restrict__ cls_w, const int* __restrict__ labels,
    const float* __restrict__ Wd1, const float* __restrict__ bd1,
    const float* __restrict__ Wd2, const float* __restrict__ bd2,
    float* __restrict__ zsn_ws, float* __restrict__ zpn_ws,
    float* __restrict__ out) {
  const int f = blockIdx.x, j = threadIdx.x;  // j < 128
  __shared__ float hf[256];
  __shared__ float zsS[128];
  __shared__ float red[128];
  hf[j] = hf_ws[f * 256 + j];
  hf[j + 128] = hf_ws[f * 256 + 128 + j];
  __syncthreads();
  float zs = bs[j], zp = bp[j];
  for (int c = 0; c < 256; ++c) {
    float hv = hf[c];
    zs += hv * Ws[c * 128 + j];
    zp += hv * Wp[c * 128 + j];
  }
  out[66048 + f * 128 + j] = zs;
  out[98816 + f * 128 + j] = zp;
  zsS[j] = zs;
  // row norms
  red[j] = zs * zs; __syncthreads();
  for (int s = 64; s > 0; s >>= 1) { if (j < s) red[j] += red[j + s]; __syncthreads(); }
  float ns = sqrtf(red[0]); __syncthreads();
  float zsn = zs / fmaxf(ns, 1e-12f);
  zsn_ws[f * 128 + j] = zsn;
  red[j] = zp * zp; __syncthreads();
  for (int s = 64; s > 0; s >>= 1) { if (j < s) red[j] += red[j + s]; __syncthreads(); }
  float npn = sqrtf(red[0]); __syncthreads();
  zpn_ws[f * 128 + j] = zp / fmaxf(npn, 1e-12f);
  // AM-softmax logits: cos_k = <zsn, cls_w[:,k]> / ||cls_w[:,k]||
  float c0 = 0.f, c1 = 0.f;
#pragma unroll
  for (int k = 0; k < 2; ++k) {
    float cw = cls_w[j * 2 + k];
    red[j] = zsn * cw; __syncthreads();
    for (int s = 64; s > 0; s >>= 1) { if (j < s) red[j] += red[j + s]; __syncthreads(); }
    float dk = red[0]; __syncthreads();
    red[j] = cw * cw; __syncthreads();
    for (int s = 64; s > 0; s >>= 1) { if (j < s) red[j] += red[j + s]; __syncthreads(); }
    float nk = sqrtf(red[0]); __syncthreads();
    float cosv = dk / fmaxf(nk, 1e-12f);
    if (k == 0) c0 = cosv; else c1 = cosv;
  }
  if (j < 2) {
    int lab = labels[f];
    float cv = (j == 0) ? c0 : c1;
    out[f * 2 + j] = 30.0f * (cv - 0.35f * (lab == j ? 1.f : 0.f));
  }
  // domain head (uses raw z_shared)
  float dd = bd1[j];
  for (int a = 0; a < 128; ++a) dd += zsS[a] * Wd1[a * 128 + j];
  dd = fmaxf(dd, 0.f);
#pragma unroll
  for (int k = 0; k < 2; ++k) {
    red[j] = dd * Wd2[j * 2 + k]; __syncthreads();
    for (int s = 64; s > 0; s >>= 1) { if (j < s) red[j] += red[j + s]; __syncthreads(); }
    if (j == 0) out[164352 + f * 2 + k] = red[0] + bd2[k];
    __syncthreads();
  }
}

// ---------------- ortho: ||zsn^T @ zpn||_F --------------------------------
__global__ __launch_bounds__(128) void ortho_partial(const float* __restrict__ zsn,
                                                     const float* __restrict__ zpn,
                                                     float* __restrict__ partial) {
  const int a = blockIdx.x, b = threadIdx.x;
  float s = 0.f;
  for (int f = 0; f < 256; ++f) s += zsn[f * 128 + a] * zpn[f * 128 + b];
  __shared__ float red[128];
  red[b] = s * s; __syncthreads();
  for (int st = 64; st > 0; st >>= 1) { if (b < st) red[b] += red[b + st]; __syncthreads(); }
  if (b == 0) partial[a] = red[0];
}

__global__ __launch_bounds__(128) void ortho_final(const float* __restrict__ partial,
                                                   float* __restrict__ out) {
  const int t = threadIdx.x;
  __shared__ float red[128];
  red[t] = partial[t]; __syncthreads();
  for (int st = 64; st > 0; st >>= 1) { if (t < st) red[t] += red[t + st]; __syncthreads(); }
  if (t == 0) out[164864] = sqrtf(red[0]);
}

extern "C" void kernel_launch(void* const* d_in, const int* in_sizes, int n_in,
                              void* d_out, int out_size, void* d_ws, size_t ws_size,
                              hipStream_t stream) {
  const float* line_emb = (const float*)d_in[0];
  const float* W1     = (const float*)d_in[1];
  const float* b1     = (const float*)d_in[2];
  const float* W2     = (const float*)d_in[3];
  const float* b2     = (const float*)d_in[4];
  const float* attn_w = (const float*)d_in[5];
  const float* attn_b = (const float*)d_in[6];
  const float* Ws     = (const float*)d_in[7];
  const float* bs     = (const float*)d_in[8];
  const float* Wp     = (const float*)d_in[9];
  const float* bp     = (const float*)d_in[10];
  const float* cls_w  = (const float*)d_in[11];
  const float* Wd1    = (const float*)d_in[12];
  const float* bd1    = (const float*)d_in[13];
  const float* Wd2    = (const float*)d_in[14];
  const float* bd2    = (const float*)d_in[15];
  const int* labels   = (const int*)d_in[18];

  char* ws = (char*)d_ws;
  unsigned short* W1t = (unsigned short*)(ws + 0);          // 768*256*2   = 393216
  unsigned short* W2t = (unsigned short*)(ws + 393216);     // 256*256*2   = 131072
  unsigned short* Abf = (unsigned short*)(ws + 524288);     // 32768*768*2 = 50331648
  float* hbuf         = (float*)(ws + 524288);              // overlays Abf (dead by then)
  float* H            = (float*)(ws + 50855936);            // 32768*256*4 = 33554432
  unsigned short* G1  = (unsigned short*)(ws + 84410368);   // 32768*256*2 = 16777216
  float* hf           = (float*)(ws + 101187584);           // 256*256*4   = 262144
  float* zsn          = (float*)(ws + 101449728);           // 256*128*4   = 131072
  float* zpn          = (float*)(ws + 101580800);           // 256*128*4   = 131072
  float* partial      = (float*)(ws + 101711872);           // 128*4
  float* out          = (float*)d_out;

  // 0. conversions
  cvt_bf16<<<dim3((32768L * 768 / 4 + 255) / 256), dim3(256), 0, stream>>>(
      line_emb, Abf, 32768L * 768 / 4);
  cvt_transpose<<<dim3((768 * 256 + 255) / 256), dim3(256), 0, stream>>>(W1, W1t, 768, 256);
  cvt_transpose<<<dim3((256 * 256 + 255) / 256), dim3(256), 0, stream>>>(W2, W2t, 256, 256);
  // 1-4. GCN layers
  gemm_bt<<<dim3(256, 2), dim3(256), 0, stream>>>(Abf, W1t, H, 32768, 256, 768);
  gcn_stencil<<<dim3(32768), dim3(256), 0, stream>>>(H, b1, G1, (float*)nullptr, 0);
  gemm_bt<<<dim3(256, 2), dim3(256), 0, stream>>>(G1, W2t, H, 32768, 256, 256);
  gcn_stencil<<<dim3(32768), dim3(256), 0, stream>>>(H, b2, (unsigned short*)nullptr, hbuf, 1);
  // 5-7. pooling + heads + ortho
  attn_pool<<<dim3(256), dim3(256), 0, stream>>>(hbuf, attn_w, attn_b, hf, out);
  head_kernel<<<dim3(256), dim3(128), 0, stream>>>(hf, Ws, bs, Wp, bp, cls_w, labels,
                                                   Wd1, bd1, Wd2, bd2, zsn, zpn, out);
  ortho_partial<<<dim3(128), dim3(128), 0, stream>>>(zsn, zpn, partial);
  ortho_final<<<dim3(1), dim3(128), 0, stream>>>(partial, out);
}

// Round 3
// 121.643 us; speedup vs baseline: 1.6157x; 1.6157x over previous
//
#include <hip/hip_runtime.h>

// GraphCodeBertCPDP forward on MI355X (gfx950) — round 3: layer fusion.
// Key fact: GEMM row-tile of 128 == one file, and the GCN graph is a within-file
// 5-tap stencil -> the full per-line hidden matrix never needs to hit HBM.
//   fused_gcn1: per file: G1 = bf16(relu(stencil(line_emb_f32 @ W1) + b1))
//               (A converted f32->bf16 in-register during staging; B via global_load_lds)
//   fused_gcn2: per file: h = stencil(G1 @ W2) + b2  (kept in LDS), then
//               in-block attention pooling -> h_file, att_weights
//   head_kernel + ortho: unchanged small per-file kernels
// Output layout (f32): [0:512) logits_cls | [512:66048) h_file |
//   [66048:98816) z_shared | [98816:131584) z_private | [131584:164352) att_w
//   [164352:164864) domain_logits | [164864] ortho

typedef __attribute__((ext_vector_type(8))) short bf16x8;
typedef __attribute__((ext_vector_type(4))) short bf16x4;
typedef __attribute__((ext_vector_type(4))) float f32x4;

__device__ __forceinline__ unsigned short f2bf(float f) {
  union { float f; unsigned int i; } v; v.f = f;
  unsigned int r = v.i + 0x7FFFu + ((v.i >> 16) & 1u);
  return (unsigned short)(r >> 16);
}
__device__ __forceinline__ int degf(int p) {  // degree+1 (self-loop) at position p
  return 5 - (p < 2 ? 2 - p : 0) - (p > 125 ? p - 125 : 0);
}

// ------------- convert + transpose: dst[C][R] = bf16(src[R][C]) -----------
__global__ void cvt_transpose(const float* __restrict__ src,
                              unsigned short* __restrict__ dst, int R, int C) {
  int idx = blockIdx.x * 256 + threadIdx.x;
  if (idx >= R * C) return;
  int cc = idx / R, rr = idx - cc * R;
  dst[idx] = f2bf(src[rr * C + cc]);
}

// ---------------- fused layer 1: GEMM(128x256x768) + stencil + relu -------
// grid = 256 files, 512 threads (8 waves as 2x4 of 64x64 tiles). BK=128.
__global__ __launch_bounds__(512) void fused_gcn1(const float* __restrict__ A,
                                                  const unsigned short* __restrict__ Bt,
                                                  const float* __restrict__ bias,
                                                  unsigned short* __restrict__ G1) {
  __shared__ __align__(16) char lds[131072];
  unsigned short* sA = (unsigned short*)lds;            // [128][128] bf16 (32 KB)
  unsigned short* sB = (unsigned short*)(lds + 32768);  // [256][128] bf16 (64 KB)
  float* hL = (float*)lds;                              // [128][256] f32 (128 KB, after K-loop)
  const int t = threadIdx.x;
  const int wave = t >> 6, lane = t & 63;
  const int wr = wave >> 2, wc = wave & 3;
  const long rowA = (long)blockIdx.x * 128;

  f32x4 acc[4][4];
#pragma unroll
  for (int m = 0; m < 4; ++m)
#pragma unroll
    for (int n = 0; n < 4; ++n) acc[m][n] = (f32x4)0.0f;

  for (int kt = 0; kt < 768; kt += 128) {
    // stage A: 128x128 f32 -> bf16 in-register -> LDS
#pragma unroll
    for (int it = 0; it < 8; ++it) {
      int i = (it * 512 + t) * 4;          // element index, 4 consecutive k
      int r = i >> 7, kk = i & 127;
      f32x4 v = *(const f32x4*)&A[(rowA + r) * 768 + kt + kk];
      unsigned short o[4];
#pragma unroll
      for (int j = 0; j < 4; ++j) o[j] = f2bf(v[j]);
      *(bf16x4*)&sA[r * 128 + kk] = *(bf16x4*)o;
    }
    // stage B: [256][128] bf16 via global_load_lds (16 B/lane, linear dst)
#pragma unroll
    for (int it = 0; it < 8; ++it) {
      int flat = (it * 512 + t) * 8;       // starting element
      int n = flat >> 7, k = flat & 127;
      const unsigned short* g = Bt + n * 768 + kt + k;
      __builtin_amdgcn_global_load_lds(
          (const __attribute__((address_space(1))) unsigned int*)g,
          (__attribute__((address_space(3))) unsigned int*)&sB[it * 4096 + wave * 512],
          16, 0, 0);
    }
    __syncthreads();
#pragma unroll
    for (int kk = 0; kk < 128; kk += 32) {
      const int kb = kk + (lane >> 4) * 8;
      bf16x8 af[4], bfr[4];
#pragma unroll
      for (int m = 0; m < 4; ++m)
        af[m] = *(const bf16x8*)&sA[(wr * 64 + m * 16 + (lane & 15)) * 128 + kb];
#pragma unroll
      for (int n = 0; n < 4; ++n)
        bfr[n] = *(const bf16x8*)&sB[(wc * 64 + n * 16 + (lane & 15)) * 128 + kb];
#pragma unroll
      for (int m = 0; m < 4; ++m)
#pragma unroll
        for (int n = 0; n < 4; ++n)
          acc[m][n] = __builtin_amdgcn_mfma_f32_16x16x32_bf16(af[m], bfr[n], acc[m][n], 0, 0, 0);
    }
    __syncthreads();
  }
  // acc -> hL  (C/D layout: col=lane&15, row=(lane>>4)*4+j)
#pragma unroll
  for (int m = 0; m < 4; ++m)
#pragma unroll
    for (int n = 0; n < 4; ++n) {
      int r = wr * 64 + m * 16 + (lane >> 4) * 4;
      int c = wc * 64 + n * 16 + (lane & 15);
#pragma unroll
      for (int j = 0; j < 4; ++j) hL[(r + j) * 256 + c] = acc[m][n][j];
    }
  __syncthreads();
  // stencil + bias + relu -> G1 (bf16)
#pragma unroll
  for (int it = 0; it < 16; ++it) {
    int g = it * 512 + t;                 // group of 4 channels
    int l = g >> 6, c0 = (g & 63) * 4;
    int dl = degf(l);
    f32x4 s = (f32x4)0.0f;
#pragma unroll
    for (int o = -2; o <= 2; ++o) {
      int q = l + o;
      if (q < 0 || q > 127) continue;
      float w = __frsqrt_rn((float)(dl * degf(q)));
      f32x4 hv = *(const f32x4*)&hL[q * 256 + c0];
      s += w * hv;
    }
    f32x4 b = *(const f32x4*)&bias[c0];
    unsigned short o4[4];
#pragma unroll
    for (int j = 0; j < 4; ++j) o4[j] = f2bf(fmaxf(s[j] + b[j], 0.f));
    *(bf16x4*)&G1[(rowA + l) * 256 + c0] = *(bf16x4*)o4;
  }
}

// ------- fused layer 2: GEMM(128x256x256) + stencil + attention pool ------
__global__ __launch_bounds__(512) void fused_gcn2(const unsigned short* __restrict__ A,
                                                  const unsigned short* __restrict__ Bt,
                                                  const float* __restrict__ bias,
                                                  const float* __restrict__ attn_w,
                                                  const float* __restrict__ attn_b,
                                                  float* __restrict__ hf_ws,
                                                  float* __restrict__ out) {
  __shared__ __align__(16) char lds[131072];
  unsigned short* sA = (unsigned short*)lds;            // [128][128] bf16
  unsigned short* sB = (unsigned short*)(lds + 32768);  // [256][128] bf16
  float* hL = (float*)lds;                              // [128][256] f32
  __shared__ float lgS[128];
  __shared__ float red[128];
  __shared__ float half1[256];
  const int t = threadIdx.x;
  const int wave = t >> 6, lane = t & 63;
  const int wr = wave >> 2, wc = wave & 3;
  const int file = blockIdx.x;
  const long rowA = (long)file * 128;

  f32x4 acc[4][4];
#pragma unroll
  for (int m = 0; m < 4; ++m)
#pragma unroll
    for (int n = 0; n < 4; ++n) acc[m][n] = (f32x4)0.0f;

  for (int kt = 0; kt < 256; kt += 128) {
#pragma unroll
    for (int it = 0; it < 4; ++it) {       // stage A tile [128][128] bf16
      int flat = (it * 512 + t) * 8;
      int r = flat >> 7, k = flat & 127;
      const unsigned short* g = A + (rowA + r) * 256 + kt + k;
      __builtin_amdgcn_global_load_lds(
          (const __attribute__((address_space(1))) unsigned int*)g,
          (__attribute__((address_space(3))) unsigned int*)&sA[it * 4096 + wave * 512],
          16, 0, 0);
    }
#pragma unroll
    for (int it = 0; it < 8; ++it) {       // stage B tile [256][128] bf16
      int flat = (it * 512 + t) * 8;
      int n = flat >> 7, k = flat & 127;
      const unsigned short* g = Bt + n * 256 + kt + k;
      __builtin_amdgcn_global_load_lds(
          (const __attribute__((address_space(1))) unsigned int*)g,
          (__attribute__((address_space(3))) unsigned int*)&sB[it * 4096 + wave * 512],
          16, 0, 0);
    }
    __syncthreads();
#pragma unroll
    for (int kk = 0; kk < 128; kk += 32) {
      const int kb = kk + (lane >> 4) * 8;
      bf16x8 af[4], bfr[4];
#pragma unroll
      for (int m = 0; m < 4; ++m)
        af[m] = *(const bf16x8*)&sA[(wr * 64 + m * 16 + (lane & 15)) * 128 + kb];
#pragma unroll
      for (int n = 0; n < 4; ++n)
        bfr[n] = *(const bf16x8*)&sB[(wc * 64 + n * 16 + (lane & 15)) * 128 + kb];
#pragma unroll
      for (int m = 0; m < 4; ++m)
#pragma unroll
        for (int n = 0; n < 4; ++n)
          acc[m][n] = __builtin_amdgcn_mfma_f32_16x16x32_bf16(af[m], bfr[n], acc[m][n], 0, 0, 0);
    }
    __syncthreads();
  }
  // acc -> hL
#pragma unroll
  for (int m = 0; m < 4; ++m)
#pragma unroll
    for (int n = 0; n < 4; ++n) {
      int r = wr * 64 + m * 16 + (lane >> 4) * 4;
      int c = wc * 64 + n * 16 + (lane & 15);
#pragma unroll
      for (int j = 0; j < 4; ++j) hL[(r + j) * 256 + c] = acc[m][n][j];
    }
  __syncthreads();
  // stencil + bias into registers (16 x f32x4), then write back in place
  f32x4 st[16];
#pragma unroll
  for (int it = 0; it < 16; ++it) {
    int g = it * 512 + t;
    int l = g >> 6, c0 = (g & 63) * 4;
    int dl = degf(l);
    f32x4 s = (f32x4)0.0f;
#pragma unroll
    for (int o = -2; o <= 2; ++o) {
      int q = l + o;
      if (q < 0 || q > 127) continue;
      float w = __frsqrt_rn((float)(dl * degf(q)));
      s += w * *(const f32x4*)&hL[q * 256 + c0];
    }
    f32x4 b = *(const f32x4*)&bias[c0];
    st[it] = s + b;
  }
  __syncthreads();
#pragma unroll
  for (int it = 0; it < 16; ++it) {
    int g = it * 512 + t;
    int l = g >> 6, c0 = (g & 63) * 4;
    *(f32x4*)&hL[l * 256 + c0] = st[it];
  }
  __syncthreads();
  // ---- attention pooling (h resident in LDS) ----
  // logits: 4 lanes per line, lane-rotated channel order (2-way banks max)
  {
    int l = t >> 2, prt = t & 3;
    float part = 0.f;
#pragma unroll 8
    for (int j = 0; j < 64; ++j) {
      int c = prt * 64 + ((j + t) & 63);
      part += hL[l * 256 + c] * attn_w[c];
    }
    part += __shfl_xor(part, 1);
    part += __shfl_xor(part, 2);
    if (prt == 0) lgS[l] = part + attn_b[0];
  }
  __syncthreads();
  if (t < 64) red[t] = fmaxf(lgS[t], lgS[t + 64]);
  __syncthreads();
  for (int s = 32; s > 0; s >>= 1) {
    if (t < s) red[t] = fmaxf(red[t], red[t + s]);
    __syncthreads();
  }
  float mx = red[0];
  __syncthreads();
  if (t < 128) lgS[t] = expf(lgS[t] - mx);
  __syncthreads();
  if (t < 64) red[t] = lgS[t] + lgS[t + 64];
  __syncthreads();
  for (int s = 32; s > 0; s >>= 1) {
    if (t < s) red[t] += red[t + s];
    __syncthreads();
  }
  float dn = red[0];
  __syncthreads();
  if (t < 128) {
    float w = lgS[t] / dn;
    lgS[t] = w;
    out[131584 + file * 128 + t] = w;
  }
  __syncthreads();
  // h_file[c] = sum_l w[l] * h[l][c]; 2 halves of lines per channel
  {
    int c = t & 255, half = t >> 8;
    float s = 0.f;
    for (int l = half * 64; l < half * 64 + 64; ++l) s += lgS[l] * hL[l * 256 + c];
    if (half == 1) half1[c] = s;
    __syncthreads();
    if (half == 0) {
      float tot = s + half1[c];
      hf_ws[file * 256 + c] = tot;
      out[512 + file * 256 + c] = tot;
    }
  }
}

// ---------------- per-file heads: z_shared/z_private/cls/domain -----------
__global__ __launch_bounds__(128) void head_kernel(const float* __restrict__ hf_ws,
    const float* __restrict__ Ws, const float* __restrict__ bs,
    const float* __restrict__ Wp, const float* __restrict__ bp,
    const float* __restrict__ cls_w, const int* __restrict__ labels,
    const float* __restrict__ Wd1, const float* __restrict__ bd1,
    const float* __restrict__ Wd2, const float* __restrict__ bd2,
    float* __restrict__ zsn_ws, float* __restrict__ zpn_ws,
    float* __restrict__ out) {
  const int f = blockIdx.x, j = threadIdx.x;  // j < 128
  __shared__ float hf[256];
  __shared__ float zsS[128];
  __shared__ float red[128];
  hf[j] = hf_ws[f * 256 + j];
  hf[j + 128] = hf_ws[f * 256 + 128 + j];
  __syncthreads();
  float zs = bs[j], zp = bp[j];
  for (int c = 0; c < 256; ++c) {
    float hv = hf[c];
    zs += hv * Ws[c * 128 + j];
    zp += hv * Wp[c * 128 + j];
  }
  out[66048 + f * 128 + j] = zs;
  out[98816 + f * 128 + j] = zp;
  zsS[j] = zs;
  red[j] = zs * zs; __syncthreads();
  for (int s = 64; s > 0; s >>= 1) { if (j < s) red[j] += red[j + s]; __syncthreads(); }
  float ns = sqrtf(red[0]); __syncthreads();
  float zsn = zs / fmaxf(ns, 1e-12f);
  zsn_ws[f * 128 + j] = zsn;
  red[j] = zp * zp; __syncthreads();
  for (int s = 64; s > 0; s >>= 1) { if (j < s) red[j] += red[j + s]; __syncthreads(); }
  float npn = sqrtf(red[0]); __syncthreads();
  zpn_ws[f * 128 + j] = zp / fmaxf(npn, 1e-12f);
  float c0 = 0.f, c1 = 0.f;
#pragma unroll
  for (int k = 0; k < 2; ++k) {
    float cw = cls_w[j * 2 + k];
    red[j] = zsn * cw; __syncthreads();
    for (int s = 64; s > 0; s >>= 1) { if (j < s) red[j] += red[j + s]; __syncthreads(); }
    float dk = red[0]; __syncthreads();
    red[j] = cw * cw; __syncthreads();
    for (int s = 64; s > 0; s >>= 1) { if (j < s) red[j] += red[j + s]; __syncthreads(); }
    float nk = sqrtf(red[0]); __syncthreads();
    float cosv = dk / fmaxf(nk, 1e-12f);
    if (k == 0) c0 = cosv; else c1 = cosv;
  }
  if (j < 2) {
    int lab = labels[f];
    float cv = (j == 0) ? c0 : c1;
    out[f * 2 + j] = 30.0f * (cv - 0.35f * (lab == j ? 1.f : 0.f));
  }
  float dd = bd1[j];
  for (int a = 0; a < 128; ++a) dd += zsS[a] * Wd1[a * 128 + j];
  dd = fmaxf(dd, 0.f);
#pragma unroll
  for (int k = 0; k < 2; ++k) {
    red[j] = dd * Wd2[j * 2 + k]; __syncthreads();
    for (int s = 64; s > 0; s >>= 1) { if (j < s) red[j] += red[j + s]; __syncthreads(); }
    if (j == 0) out[164352 + f * 2 + k] = red[0] + bd2[k];
    __syncthreads();
  }
}

// ---------------- ortho: ||zsn^T @ zpn||_F --------------------------------
__global__ __launch_bounds__(128) void ortho_partial(const float* __restrict__ zsn,
                                                     const float* __restrict__ zpn,
                                                     float* __restrict__ partial) {
  const int a = blockIdx.x, b = threadIdx.x;
  float s = 0.f;
  for (int f = 0; f < 256; ++f) s += zsn[f * 128 + a] * zpn[f * 128 + b];
  __shared__ float red[128];
  red[b] = s * s; __syncthreads();
  for (int st = 64; st > 0; st >>= 1) { if (b < st) red[b] += red[b + st]; __syncthreads(); }
  if (b == 0) partial[a] = red[0];
}

__global__ __launch_bounds__(128) void ortho_final(const float* __restrict__ partial,
                                                   float* __restrict__ out) {
  const int t = threadIdx.x;
  __shared__ float red[128];
  red[t] = partial[t]; __syncthreads();
  for (int st = 64; st > 0; st >>= 1) { if (t < st) red[t] += red[t + st]; __syncthreads(); }
  if (t == 0) out[164864] = sqrtf(red[0]);
}

extern "C" void kernel_launch(void* const* d_in, const int* in_sizes, int n_in,
                              void* d_out, int out_size, void* d_ws, size_t ws_size,
                              hipStream_t stream) {
  const float* line_emb = (const float*)d_in[0];
  const float* W1     = (const float*)d_in[1];
  const float* b1     = (const float*)d_in[2];
  const float* W2     = (const float*)d_in[3];
  const float* b2     = (const float*)d_in[4];
  const float* attn_w = (const float*)d_in[5];
  const float* attn_b = (const float*)d_in[6];
  const float* Ws     = (const float*)d_in[7];
  const float* bs     = (const float*)d_in[8];
  const float* Wp     = (const float*)d_in[9];
  const float* bp     = (const float*)d_in[10];
  const float* cls_w  = (const float*)d_in[11];
  const float* Wd1    = (const float*)d_in[12];
  const float* bd1    = (const float*)d_in[13];
  const float* Wd2    = (const float*)d_in[14];
  const float* bd2    = (const float*)d_in[15];
  const int* labels   = (const int*)d_in[18];

  char* ws = (char*)d_ws;
  unsigned short* W1t = (unsigned short*)(ws + 0);          // [256][768] bf16
  unsigned short* W2t = (unsigned short*)(ws + 393216);     // [256][256] bf16
  unsigned short* G1  = (unsigned short*)(ws + 524288);     // [32768][256] bf16
  float* hf           = (float*)(ws + 17301504);            // [256][256] f32
  float* zsn          = (float*)(ws + 17563648);
  float* zpn          = (float*)(ws + 17694720);
  float* partial      = (float*)(ws + 17825792);
  float* out          = (float*)d_out;

  cvt_transpose<<<dim3((768 * 256 + 255) / 256), dim3(256), 0, stream>>>(W1, W1t, 768, 256);
  cvt_transpose<<<dim3((256 * 256 + 255) / 256), dim3(256), 0, stream>>>(W2, W2t, 256, 256);
  fused_gcn1<<<dim3(256), dim3(512), 0, stream>>>(line_emb, W1t, b1, G1);
  fused_gcn2<<<dim3(256), dim3(512), 0, stream>>>(G1, W2t, b2, attn_w, attn_b, hf, out);
  head_kernel<<<dim3(256), dim3(128), 0, stream>>>(hf, Ws, bs, Wp, bp, cls_w, labels,
                                                   Wd1, bd1, Wd2, bd2, zsn, zpn, out);
  ortho_partial<<<dim3(128), dim3(128), 0, stream>>>(zsn, zpn, partial);
  ortho_final<<<dim3(1), dim3(128), 0, stream>>>(partial, out);
}

// Round 4
// 82.797 us; speedup vs baseline: 2.3737x; 1.4692x over previous
//
#include <hip/hip_runtime.h>

// GraphCodeBertCPDP forward on MI355X (gfx950) — round 4.
// Fixes vs round 3 (latency-bound fused_gcn1 @ 2 waves/SIMD, serial staging):
//  - 1024-thread blocks (16 waves, 4/SIMD), wave grid 4x4 of 32x64 output tiles
//  - 2-phase prefetch, BK=64, double-buffered LDS; A reg-staged (1 f32x8/thread),
//    B via async global_load_lds issued before MFMA phase
//  - T2 XOR swizzle (col ^= (row&7)<<3 in 8-elt groups) on both write & read;
//    B uses pre-swizzled GLOBAL source with linear DMA dst (m173 pattern)
// Output layout (f32): [0:512) logits_cls | [512:66048) h_file |
//   [66048:98816) z_shared | [98816:131584) z_private | [131584:164352) att_w
//   [164352:164864) domain_logits | [164864] ortho

typedef __attribute__((ext_vector_type(8))) short bf16x8;
typedef __attribute__((ext_vector_type(4))) short bf16x4;
typedef __attribute__((ext_vector_type(4))) float f32x4;
typedef __attribute__((ext_vector_type(8))) float f32x8;

__device__ __forceinline__ unsigned short f2bf(float f) {
  union { float f; unsigned int i; } v; v.f = f;
  unsigned int r = v.i + 0x7FFFu + ((v.i >> 16) & 1u);
  return (unsigned short)(r >> 16);
}
__device__ __forceinline__ int degf(int p) {  // degree+1 (self-loop)
  return 5 - (p < 2 ? 2 - p : 0) - (p > 125 ? p - 125 : 0);
}

// ---------- tiled convert+transpose: dst[C][R] = bf16(src[R][C]) ----------
__global__ void cvt_transpose_tiled(const float* __restrict__ src,
                                    unsigned short* __restrict__ dst, int R, int C) {
  __shared__ float tile[32][33];
  int bx = blockIdx.x * 32, by = blockIdx.y * 32;
  int tx = threadIdx.x, ty = threadIdx.y;  // 32 x 8
#pragma unroll
  for (int j = 0; j < 32; j += 8)
    tile[ty + j][tx] = src[(by + ty + j) * C + bx + tx];
  __syncthreads();
#pragma unroll
  for (int j = 0; j < 32; j += 8)
    dst[(bx + ty + j) * R + by + tx] = f2bf(tile[tx][ty + j]);
}

// ---------------- fused layer 1: GEMM(128x256x768) + stencil + relu -------
// grid = 256 files, 1024 threads (16 waves as 4x4 of 32x64 tiles).
__global__ __launch_bounds__(1024) void fused_gcn1(const float* __restrict__ A,
                                                   const unsigned short* __restrict__ Bt,
                                                   const float* __restrict__ bias,
                                                   unsigned short* __restrict__ G1) {
  __shared__ __align__(16) char lds[131072];
  unsigned short* sA = (unsigned short*)lds;            // [2][128][64] bf16 (32 KB)
  unsigned short* sB = (unsigned short*)(lds + 32768);  // [2][256][64] bf16 (64 KB)
  float* hL = (float*)lds;                              // [128][256] f32 (after K loop)
  const int t = threadIdx.x;
  const int wave = t >> 6, lane = t & 63;
  const int wr = wave >> 2, wc = wave & 3;              // 4x4 waves
  const long rowA = (long)blockIdx.x * 128;

  f32x4 acc[2][4];
#pragma unroll
  for (int m = 0; m < 2; ++m)
#pragma unroll
    for (int n = 0; n < 4; ++n) acc[m][n] = (f32x4)0.0f;

  const int arow = t >> 3, acol = (t & 7) * 8;          // A stage: 1 f32x8/thread
  const int aswz = arow * 64 + (acol ^ ((arow & 7) << 3));
  const int NKT = 12;                                   // 768/64
  f32x8 areg;

#define ISSUE_A1(kt) areg = *(const f32x8*)&A[(rowA + arow) * 768 + (kt) * 64 + acol]
#define WRITE_A1(buf) { unsigned short u[8];                                      \
    _Pragma("unroll") for (int j = 0; j < 8; ++j) u[j] = f2bf(areg[j]);           \
    *(bf16x8*)&sA[(buf) * 8192 + aswz] = *(bf16x8*)u; }
#define ISSUE_B1(kt, buf) _Pragma("unroll") for (int it = 0; it < 2; ++it) {      \
    int flat = (it * 1024 + t) * 8;                                               \
    int n = flat >> 6, k = flat & 63;                                             \
    const unsigned short* g = Bt + n * 768 + (kt) * 64 + (k ^ ((n & 7) << 3));    \
    __builtin_amdgcn_global_load_lds(                                             \
        (const __attribute__((address_space(1))) unsigned int*)g,                 \
        (__attribute__((address_space(3))) unsigned int*)                         \
            &sB[(buf) * 16384 + (it * 16 + wave) * 512], 16, 0, 0); }

  ISSUE_A1(0); ISSUE_B1(0, 0); WRITE_A1(0);
  __syncthreads();
  for (int kt = 0; kt < NKT; ++kt) {
    const int cur = kt & 1, nxt = cur ^ 1;
    if (kt + 1 < NKT) { ISSUE_A1(kt + 1); ISSUE_B1(kt + 1, nxt); }
#pragma unroll
    for (int kk = 0; kk < 2; ++kk) {
      const int kb = kk * 32 + (lane >> 4) * 8;
      bf16x8 af[2], bfr[4];
#pragma unroll
      for (int m = 0; m < 2; ++m) {
        int r = wr * 32 + m * 16 + (lane & 15);
        af[m] = *(const bf16x8*)&sA[cur * 8192 + r * 64 + (kb ^ ((r & 7) << 3))];
      }
#pragma unroll
      for (int n = 0; n < 4; ++n) {
        int r = wc * 64 + n * 16 + (lane & 15);
        bfr[n] = *(const bf16x8*)&sB[cur * 16384 + r * 64 + (kb ^ ((r & 7) << 3))];
      }
#pragma unroll
      for (int m = 0; m < 2; ++m)
#pragma unroll
        for (int n = 0; n < 4; ++n)
          acc[m][n] = __builtin_amdgcn_mfma_f32_16x16x32_bf16(af[m], bfr[n], acc[m][n], 0, 0, 0);
    }
    if (kt + 1 < NKT) WRITE_A1(nxt);
    __syncthreads();
  }
  // acc -> hL  (C/D layout: col=lane&15, row=(lane>>4)*4+j)
#pragma unroll
  for (int m = 0; m < 2; ++m)
#pragma unroll
    for (int n = 0; n < 4; ++n) {
      int r = wr * 32 + m * 16 + (lane >> 4) * 4;
      int c = wc * 64 + n * 16 + (lane & 15);
#pragma unroll
      for (int j = 0; j < 4; ++j) hL[(r + j) * 256 + c] = acc[m][n][j];
    }
  __syncthreads();
  // stencil + bias + relu -> G1 (bf16)
#pragma unroll
  for (int it = 0; it < 8; ++it) {
    int g = it * 1024 + t;
    int l = g >> 6, c0 = (g & 63) * 4;
    int dl = degf(l);
    f32x4 s = (f32x4)0.0f;
#pragma unroll
    for (int o = -2; o <= 2; ++o) {
      int q = l + o;
      if (q < 0 || q > 127) continue;
      float w = __frsqrt_rn((float)(dl * degf(q)));
      s += w * *(const f32x4*)&hL[q * 256 + c0];
    }
    f32x4 b = *(const f32x4*)&bias[c0];
    unsigned short o4[4];
#pragma unroll
    for (int j = 0; j < 4; ++j) o4[j] = f2bf(fmaxf(s[j] + b[j], 0.f));
    *(bf16x4*)&G1[(rowA + l) * 256 + c0] = *(bf16x4*)o4;
  }
#undef ISSUE_A1
#undef WRITE_A1
#undef ISSUE_B1
}

// ------- fused layer 2: GEMM(128x256x256) + stencil + attention pool ------
__global__ __launch_bounds__(1024) void fused_gcn2(const unsigned short* __restrict__ A,
                                                   const unsigned short* __restrict__ Bt,
                                                   const float* __restrict__ bias,
                                                   const float* __restrict__ attn_w,
                                                   const float* __restrict__ attn_b,
                                                   float* __restrict__ hf_ws,
                                                   float* __restrict__ out) {
  __shared__ __align__(16) char lds[131072];
  unsigned short* sA = (unsigned short*)lds;            // [2][128][64] bf16
  unsigned short* sB = (unsigned short*)(lds + 32768);  // [2][256][64] bf16
  float* hL = (float*)lds;                              // [128][256] f32
  __shared__ float awS[256];
  __shared__ float lgS[128];
  __shared__ float red[64];
  __shared__ float psum[4 * 256];
  const int t = threadIdx.x;
  const int wave = t >> 6, lane = t & 63;
  const int wr = wave >> 2, wc = wave & 3;
  const int file = blockIdx.x;
  const long rowA = (long)file * 128;

  if (t < 256) awS[t] = attn_w[t];

  f32x4 acc[2][4];
#pragma unroll
  for (int m = 0; m < 2; ++m)
#pragma unroll
    for (int n = 0; n < 4; ++n) acc[m][n] = (f32x4)0.0f;

  const int NKT = 4;  // 256/64

#define ISSUE_A2(kt, buf) {                                                       \
    int flat = t * 8;                                                             \
    int r = flat >> 6, k = flat & 63;                                             \
    const unsigned short* g = A + (rowA + r) * 256 + (kt) * 64 + (k ^ ((r & 7) << 3)); \
    __builtin_amdgcn_global_load_lds(                                             \
        (const __attribute__((address_space(1))) unsigned int*)g,                 \
        (__attribute__((address_space(3))) unsigned int*)                         \
            &sA[(buf) * 8192 + wave * 512], 16, 0, 0); }
#define ISSUE_B2(kt, buf) _Pragma("unroll") for (int it = 0; it < 2; ++it) {      \
    int flat = (it * 1024 + t) * 8;                                               \
    int n = flat >> 6, k = flat & 63;                                             \
    const unsigned short* g = Bt + n * 256 + (kt) * 64 + (k ^ ((n & 7) << 3));    \
    __builtin_amdgcn_global_load_lds(                                             \
        (const __attribute__((address_space(1))) unsigned int*)g,                 \
        (__attribute__((address_space(3))) unsigned int*)                         \
            &sB[(buf) * 16384 + (it * 16 + wave) * 512], 16, 0, 0); }

  ISSUE_A2(0, 0); ISSUE_B2(0, 0);
  __syncthreads();
  for (int kt = 0; kt < NKT; ++kt) {
    const int cur = kt & 1, nxt = cur ^ 1;
    if (kt + 1 < NKT) { ISSUE_A2(kt + 1, nxt); ISSUE_B2(kt + 1, nxt); }
#pragma unroll
    for (int kk = 0; kk < 2; ++kk) {
      const int kb = kk * 32 + (lane >> 4) * 8;
      bf16x8 af[2], bfr[4];
#pragma unroll
      for (int m = 0; m < 2; ++m) {
        int r = wr * 32 + m * 16 + (lane & 15);
        af[m] = *(const bf16x8*)&sA[cur * 8192 + r * 64 + (kb ^ ((r & 7) << 3))];
      }
#pragma unroll
      for (int n = 0; n < 4; ++n) {
        int r = wc * 64 + n * 16 + (lane & 15);
        bfr[n] = *(const bf16x8*)&sB[cur * 16384 + r * 64 + (kb ^ ((r & 7) << 3))];
      }
#pragma unroll
      for (int m = 0; m < 2; ++m)
#pragma unroll
        for (int n = 0; n < 4; ++n)
          acc[m][n] = __builtin_amdgcn_mfma_f32_16x16x32_bf16(af[m], bfr[n], acc[m][n], 0, 0, 0);
    }
    __syncthreads();
  }
  // acc -> hL
#pragma unroll
  for (int m = 0; m < 2; ++m)
#pragma unroll
    for (int n = 0; n < 4; ++n) {
      int r = wr * 32 + m * 16 + (lane >> 4) * 4;
      int c = wc * 64 + n * 16 + (lane & 15);
#pragma unroll
      for (int j = 0; j < 4; ++j) hL[(r + j) * 256 + c] = acc[m][n][j];
    }
  __syncthreads();
  // stencil + bias into registers, write back in place
  f32x4 st[2];
#pragma unroll
  for (int it = 0; it < 2; ++it) {
    int g = it * 1024 + t;
    int l = g >> 6, c0 = (g & 63) * 4;
    int dl = degf(l);
    f32x4 s = (f32x4)0.0f;
#pragma unroll
    for (int o = -2; o <= 2; ++o) {
      int q = l + o;
      if (q < 0 || q > 127) continue;
      float w = __frsqrt_rn((float)(dl * degf(q)));
      s += w * *(const f32x4*)&hL[q * 256 + c0];
    }
    f32x4 b = *(const f32x4*)&bias[c0];
    st[it] = s + b;
  }
  __syncthreads();
#pragma unroll
  for (int it = 0; it < 2; ++it) {
    int g = it * 1024 + t;
    int l = g >> 6, c0 = (g & 63) * 4;
    *(f32x4*)&hL[l * 256 + c0] = st[it];
  }
  __syncthreads();
  // ---- attention pooling (h resident in LDS) ----
  // logits: 8 lanes per line, rotated channel order (<=2-way banks)
  {
    int l = t >> 3, p = t & 7;
    float part = 0.f;
#pragma unroll 4
    for (int j = 0; j < 32; ++j) {
      int c = p * 32 + ((j + 4 * p + l) & 31);
      part += hL[l * 256 + c] * awS[c];
    }
    part += __shfl_xor(part, 1);
    part += __shfl_xor(part, 2);
    part += __shfl_xor(part, 4);
    if (p == 0) lgS[l] = part + attn_b[0];
  }
  __syncthreads();
  if (t < 64) red[t] = fmaxf(lgS[t], lgS[t + 64]);
  __syncthreads();
  for (int s = 32; s > 0; s >>= 1) {
    if (t < s) red[t] = fmaxf(red[t], red[t + s]);
    __syncthreads();
  }
  float mx = red[0];
  __syncthreads();
  if (t < 128) lgS[t] = expf(lgS[t] - mx);
  __syncthreads();
  if (t < 64) red[t] = lgS[t] + lgS[t + 64];
  __syncthreads();
  for (int s = 32; s > 0; s >>= 1) {
    if (t < s) red[t] += red[t + s];
    __syncthreads();
  }
  float dn = red[0];
  __syncthreads();
  if (t < 128) {
    float w = lgS[t] / dn;
    lgS[t] = w;
    out[131584 + file * 128 + t] = w;
  }
  __syncthreads();
  // h_file[c] = sum_l w[l]*h[l][c]; 4 line-groups of 32
  {
    int c = t & 255, grp = t >> 8;
    float s = 0.f;
    for (int l = grp * 32; l < grp * 32 + 32; ++l) s += lgS[l] * hL[l * 256 + c];
    psum[grp * 256 + c] = s;
  }
  __syncthreads();
  if (t < 256) {
    float tot = psum[t] + psum[256 + t] + psum[512 + t] + psum[768 + t];
    hf_ws[file * 256 + t] = tot;
    out[512 + file * 256 + t] = tot;
  }
#undef ISSUE_A2
#undef ISSUE_B2
}

// ---------------- per-file heads: z_shared/z_private/cls/domain -----------
__global__ __launch_bounds__(128) void head_kernel(const float* __restrict__ hf_ws,
    const float* __restrict__ Ws, const float* __restrict__ bs,
    const float* __restrict__ Wp, const float* __restrict__ bp,
    const float* __restrict__ cls_w, const int* __restrict__ labels,
    const float* __restrict__ Wd1, const float* __restrict__ bd1,
    const float* __restrict__ Wd2, const float* __restrict__ bd2,
    float* __restrict__ zsn_ws, float* __restrict__ zpn_ws,
    float* __restrict__ out) {
  const int f = blockIdx.x, j = threadIdx.x;  // j < 128
  __shared__ float hf[256];
  __shared__ float zsS[128];
  __shared__ float red[128];
  hf[j] = hf_ws[f * 256 + j];
  hf[j + 128] = hf_ws[f * 256 + 128 + j];
  __syncthreads();
  float zs = bs[j], zp = bp[j];
  for (int c = 0; c < 256; ++c) {
    float hv = hf[c];
    zs += hv * Ws[c * 128 + j];
    zp += hv * Wp[c * 128 + j];
  }
  out[66048 + f * 128 + j] = zs;
  out[98816 + f * 128 + j] = zp;
  zsS[j] = zs;
  red[j] = zs * zs; __syncthreads();
  for (int s = 64; s > 0; s >>= 1) { if (j < s) red[j] += red[j + s]; __syncthreads(); }
  float ns = sqrtf(red[0]); __syncthreads();
  float zsn = zs / fmaxf(ns, 1e-12f);
  zsn_ws[f * 128 + j] = zsn;
  red[j] = zp * zp; __syncthreads();
  for (int s = 64; s > 0; s >>= 1) { if (j < s) red[j] += red[j + s]; __syncthreads(); }
  float npn = sqrtf(red[0]); __syncthreads();
  zpn_ws[f * 128 + j] = zp / fmaxf(npn, 1e-12f);
  float c0 = 0.f, c1 = 0.f;
#pragma unroll
  for (int k = 0; k < 2; ++k) {
    float cw = cls_w[j * 2 + k];
    red[j] = zsn * cw; __syncthreads();
    for (int s = 64; s > 0; s >>= 1) { if (j < s) red[j] += red[j + s]; __syncthreads(); }
    float dk = red[0]; __syncthreads();
    red[j] = cw * cw; __syncthreads();
    for (int s = 64; s > 0; s >>= 1) { if (j < s) red[j] += red[j + s]; __syncthreads(); }
    float nk = sqrtf(red[0]); __syncthreads();
    float cosv = dk / fmaxf(nk, 1e-12f);
    if (k == 0) c0 = cosv; else c1 = cosv;
  }
  if (j < 2) {
    int lab = labels[f];
    float cv = (j == 0) ? c0 : c1;
    out[f * 2 + j] = 30.0f * (cv - 0.35f * (lab == j ? 1.f : 0.f));
  }
  float dd = bd1[j];
  for (int a = 0; a < 128; ++a) dd += zsS[a] * Wd1[a * 128 + j];
  dd = fmaxf(dd, 0.f);
#pragma unroll
  for (int k = 0; k < 2; ++k) {
    red[j] = dd * Wd2[j * 2 + k]; __syncthreads();
    for (int s = 64; s > 0; s >>= 1) { if (j < s) red[j] += red[j + s]; __syncthreads(); }
    if (j == 0) out[164352 + f * 2 + k] = red[0] + bd2[k];
    __syncthreads();
  }
}

// ---------------- ortho: ||zsn^T @ zpn||_F --------------------------------
__global__ __launch_bounds__(128) void ortho_partial(const float* __restrict__ zsn,
                                                     const float* __restrict__ zpn,
                                                     float* __restrict__ partial) {
  const int a = blockIdx.x, b = threadIdx.x;
  float s = 0.f;
  for (int f = 0; f < 256; ++f) s += zsn[f * 128 + a] * zpn[f * 128 + b];
  __shared__ float red[128];
  red[b] = s * s; __syncthreads();
  for (int st = 64; st > 0; st >>= 1) { if (b < st) red[b] += red[b + st]; __syncthreads(); }
  if (b == 0) partial[a] = red[0];
}

__global__ __launch_bounds__(128) void ortho_final(const float* __restrict__ partial,
                                                   float* __restrict__ out) {
  const int t = threadIdx.x;
  __shared__ float red[128];
  red[t] = partial[t]; __syncthreads();
  for (int st = 64; st > 0; st >>= 1) { if (t < st) red[t] += red[t + st]; __syncthreads(); }
  if (t == 0) out[164864] = sqrtf(red[0]);
}

extern "C" void kernel_launch(void* const* d_in, const int* in_sizes, int n_in,
                              void* d_out, int out_size, void* d_ws, size_t ws_size,
                              hipStream_t stream) {
  const float* line_emb = (const float*)d_in[0];
  const float* W1     = (const float*)d_in[1];
  const float* b1     = (const float*)d_in[2];
  const float* W2     = (const float*)d_in[3];
  const float* b2     = (const float*)d_in[4];
  const float* attn_w = (const float*)d_in[5];
  const float* attn_b = (const float*)d_in[6];
  const float* Ws     = (const float*)d_in[7];
  const float* bs     = (const float*)d_in[8];
  const float* Wp     = (const float*)d_in[9];
  const float* bp     = (const float*)d_in[10];
  const float* cls_w  = (const float*)d_in[11];
  const float* Wd1    = (const float*)d_in[12];
  const float* bd1    = (const float*)d_in[13];
  const float* Wd2    = (const float*)d_in[14];
  const float* bd2    = (const float*)d_in[15];
  const int* labels   = (const int*)d_in[18];

  char* ws = (char*)d_ws;
  unsigned short* W1t = (unsigned short*)(ws + 0);          // [256][768] bf16
  unsigned short* W2t = (unsigned short*)(ws + 393216);     // [256][256] bf16
  unsigned short* G1  = (unsigned short*)(ws + 524288);     // [32768][256] bf16
  float* hf           = (float*)(ws + 17301504);            // [256][256] f32
  float* zsn          = (float*)(ws + 17563648);
  float* zpn          = (float*)(ws + 17694720);
  float* partial      = (float*)(ws + 17825792);
  float* out          = (float*)d_out;

  cvt_transpose_tiled<<<dim3(8, 24), dim3(32, 8), 0, stream>>>(W1, W1t, 768, 256);
  cvt_transpose_tiled<<<dim3(8, 8), dim3(32, 8), 0, stream>>>(W2, W2t, 256, 256);
  fused_gcn1<<<dim3(256), dim3(1024), 0, stream>>>(line_emb, W1t, b1, G1);
  fused_gcn2<<<dim3(256), dim3(1024), 0, stream>>>(G1, W2t, b2, attn_w, attn_b, hf, out);
  head_kernel<<<dim3(256), dim3(128), 0, stream>>>(hf, Ws, bs, Wp, bp, cls_w, labels,
                                                   Wd1, bd1, Wd2, bd2, zsn, zpn, out);
  ortho_partial<<<dim3(128), dim3(128), 0, stream>>>(zsn, zpn, partial);
  ortho_final<<<dim3(1), dim3(128), 0, stream>>>(partial, out);
}

// Round 8
// 74.729 us; speedup vs baseline: 2.6299x; 1.1080x over previous
//
#include <hip/hip_runtime.h>

// GraphCodeBertCPDP forward on MI355X (gfx950) — round 8.
// FIX vs round 7: the two stencil loops covered only lines 0..31 (it<2);
// lines 32..127 of G1L/hB were never written -> phase-2 MFMA read
// uninitialized LDS -> nondeterministic garbage/NaN (rounds 5/7 failures).
// Now it<8 covers all 128 lines. No other changes.
// Launches: prep_weights, mega, znorm, ortho_partial, ortho_final.
// Output layout (f32): [0:512) logits_cls | [512:66048) h_file |
//   [66048:98816) z_shared | [98816:131584) z_private | [131584:164352) att_w
//   [164352:164864) domain_logits | [164864] ortho

typedef __attribute__((ext_vector_type(8))) short bf16x8;
typedef __attribute__((ext_vector_type(4))) short bf16x4;
typedef __attribute__((ext_vector_type(4))) float f32x4;
typedef __attribute__((ext_vector_type(8))) float f32x8;

__device__ __forceinline__ unsigned short f2bf(float f) {
  union { float f; unsigned int i; } v; v.f = f;
  unsigned int r = v.i + 0x7FFFu + ((v.i >> 16) & 1u);
  return (unsigned short)(r >> 16);
}
__device__ __forceinline__ float bf2f(unsigned short u) {
  union { unsigned int i; float f; } v; v.i = ((unsigned int)u) << 16; return v.f;
}
__device__ __forceinline__ float cvt4dot(bf16x4 v, f32x4* o) {
  (*o)[0] = bf2f(((unsigned short*)&v)[0]); (*o)[1] = bf2f(((unsigned short*)&v)[1]);
  (*o)[2] = bf2f(((unsigned short*)&v)[2]); (*o)[3] = bf2f(((unsigned short*)&v)[3]);
  return 0.f;
}
__device__ __forceinline__ int degf(int p) {  // degree+1 (self-loop)
  return 5 - (p < 2 ? 2 - p : 0) - (p > 125 ? p - 125 : 0);
}
__device__ __forceinline__ float wsum(float v) {
#pragma unroll
  for (int o = 1; o < 64; o <<= 1) v += __shfl_xor(v, o);
  return v;
}

// ---------- merged tiled convert+transpose for W1 and W2 ------------------
__global__ void prep_weights(const float* __restrict__ W1, const float* __restrict__ W2,
                             unsigned short* __restrict__ W1t, unsigned short* __restrict__ W2t) {
  __shared__ float tile[32][33];
  int id = blockIdx.x;
  const float* src; unsigned short* dst; int R, C, bx, by;
  if (id < 192) { src = W1; dst = W1t; R = 768; C = 256; bx = (id % 8) * 32; by = (id / 8) * 32; }
  else { id -= 192; src = W2; dst = W2t; R = 256; C = 256; bx = (id % 8) * 32; by = (id / 8) * 32; }
  int tx = threadIdx.x, ty = threadIdx.y;  // 32 x 8
#pragma unroll
  for (int j = 0; j < 32; j += 8)
    tile[ty + j][tx] = src[(by + ty + j) * C + bx + tx];
  __syncthreads();
#pragma unroll
  for (int j = 0; j < 32; j += 8)
    dst[(bx + ty + j) * R + by + tx] = f2bf(tile[tx][ty + j]);
}

// --------------------------- megakernel -----------------------------------
__global__ __launch_bounds__(1024) void mega(const float* __restrict__ A,
    const unsigned short* __restrict__ W1t, const float* __restrict__ b1,
    const unsigned short* __restrict__ W2t, const float* __restrict__ b2,
    const float* __restrict__ attn_w, const float* __restrict__ attn_b,
    const float* __restrict__ Ws, const float* __restrict__ bs,
    const float* __restrict__ Wp, const float* __restrict__ bp,
    const float* __restrict__ cls_w, const int* __restrict__ labels,
    const float* __restrict__ Wd1, const float* __restrict__ bd1,
    const float* __restrict__ Wd2, const float* __restrict__ bd2,
    float* __restrict__ out) {
  __shared__ __align__(16) char lds[131072];
  // phase1 staging
  unsigned short* sA1 = (unsigned short*)lds;            // [2][128][64] bf16, 32 KB
  unsigned short* sB1 = (unsigned short*)(lds + 32768);  // [2][256][64] bf16, 64 KB
  // post-phase1 overlays
  unsigned short* H1  = (unsigned short*)lds;            // [128][256] bf16, 64 KB
  unsigned short* G1L = (unsigned short*)(lds + 65536);  // [128][256] bf16 swz, 64 KB
  // phase2 overlays
  unsigned short* sB2 = (unsigned short*)lds;            // [2][256][64] bf16, 64 KB
  unsigned short* H2  = (unsigned short*)lds;            // [128][256] bf16 (after loop2)
  unsigned short* hB  = (unsigned short*)(lds + 65536);  // [128][256] bf16 (over G1L)
  __shared__ float awS[256];
  __shared__ float lgS[128];
  __shared__ float redM[64];
  __shared__ float scr[1024];
  __shared__ float hfS[256];
  __shared__ float zsS[128], znS[128];
  __shared__ float redS[16];

  const int t = threadIdx.x;
  const int wave = t >> 6, lane = t & 63;
  const int wr = wave >> 2, wc = wave & 3;              // 4x4 waves, 32x64 tiles
  const int file = blockIdx.x;
  const long rowA = (long)file * 128;

  if (t < 256) awS[t] = attn_w[t];

  f32x4 acc[2][4];
#pragma unroll
  for (int m = 0; m < 2; ++m)
#pragma unroll
    for (int n = 0; n < 4; ++n) acc[m][n] = (f32x4)0.0f;

  // ======================= phase 1: H1 = A @ W1t^T =========================
  const int arow = t >> 3, acol = (t & 7) * 8;
  const int aswz = arow * 64 + (acol ^ ((arow & 7) << 3));
  f32x8 areg;
#define ISSUE_A1(kt) areg = *(const f32x8*)&A[(rowA + arow) * 768 + (kt) * 64 + acol]
#define WRITE_A1(buf) { unsigned short u[8];                                      \
    _Pragma("unroll") for (int j = 0; j < 8; ++j) u[j] = f2bf(areg[j]);           \
    *(bf16x8*)&sA1[(buf) * 8192 + aswz] = *(bf16x8*)u; }
#define ISSUE_B1(kt, buf) _Pragma("unroll") for (int it = 0; it < 2; ++it) {      \
    int flat = (it * 1024 + t) * 8;                                               \
    int n = flat >> 6, k = flat & 63;                                             \
    const unsigned short* g = W1t + n * 768 + (kt) * 64 + (k ^ ((n & 7) << 3));   \
    __builtin_amdgcn_global_load_lds(                                             \
        (const __attribute__((address_space(1))) unsigned int*)g,                 \
        (__attribute__((address_space(3))) unsigned int*)                         \
            &sB1[(buf) * 16384 + (it * 16 + wave) * 512], 16, 0, 0); }

  ISSUE_A1(0); ISSUE_B1(0, 0); WRITE_A1(0);
  __syncthreads();
  for (int kt = 0; kt < 12; ++kt) {
    const int cur = kt & 1, nxt = cur ^ 1;
    if (kt + 1 < 12) { ISSUE_A1(kt + 1); ISSUE_B1(kt + 1, nxt); }
#pragma unroll
    for (int kk = 0; kk < 2; ++kk) {
      const int kb = kk * 32 + (lane >> 4) * 8;
      bf16x8 af[2], bfr[4];
#pragma unroll
      for (int m = 0; m < 2; ++m) {
        int r = wr * 32 + m * 16 + (lane & 15);
        af[m] = *(const bf16x8*)&sA1[cur * 8192 + r * 64 + (kb ^ ((r & 7) << 3))];
      }
#pragma unroll
      for (int n = 0; n < 4; ++n) {
        int r = wc * 64 + n * 16 + (lane & 15);
        bfr[n] = *(const bf16x8*)&sB1[cur * 16384 + r * 64 + (kb ^ ((r & 7) << 3))];
      }
#pragma unroll
      for (int m = 0; m < 2; ++m)
#pragma unroll
        for (int n = 0; n < 4; ++n)
          acc[m][n] = __builtin_amdgcn_mfma_f32_16x16x32_bf16(af[m], bfr[n], acc[m][n], 0, 0, 0);
    }
    if (kt + 1 < 12) WRITE_A1(nxt);
    __syncthreads();
  }
  // acc -> H1 (bf16).  C/D layout: col = lane&15, row = (lane>>4)*4+j
#pragma unroll
  for (int m = 0; m < 2; ++m)
#pragma unroll
    for (int n = 0; n < 4; ++n) {
      int r = wr * 32 + m * 16 + (lane >> 4) * 4;
      int c = wc * 64 + n * 16 + (lane & 15);
#pragma unroll
      for (int j = 0; j < 4; ++j) H1[(r + j) * 256 + c] = f2bf(acc[m][n][j]);
    }
  __syncthreads();
  // stencil1 + b1 + relu -> G1L (swizzled cols); it<8 covers ALL 128 lines
#pragma unroll
  for (int it = 0; it < 8; ++it) {
    int g = it * 1024 + t;
    int l = g >> 6, c0 = (g & 63) * 4;
    int dl = degf(l);
    f32x4 s = (f32x4)0.0f;
#pragma unroll
    for (int o = -2; o <= 2; ++o) {
      int q = l + o;
      if (q < 0 || q > 127) continue;
      float w = __frsqrt_rn((float)(dl * degf(q)));
      bf16x4 hv4 = *(const bf16x4*)&H1[q * 256 + c0];
      f32x4 hv; cvt4dot(hv4, &hv);
      s += w * hv;
    }
    f32x4 b = *(const f32x4*)&b1[c0];
    unsigned short o4[4];
#pragma unroll
    for (int j = 0; j < 4; ++j) o4[j] = f2bf(fmaxf(s[j] + b[j], 0.f));
    *(bf16x4*)&G1L[l * 256 + (c0 ^ ((l & 7) << 3))] = *(bf16x4*)o4;
  }
  __syncthreads();

  // ======================= phase 2: H2 = G1 @ W2t^T ========================
#pragma unroll
  for (int m = 0; m < 2; ++m)
#pragma unroll
    for (int n = 0; n < 4; ++n) acc[m][n] = (f32x4)0.0f;
#define ISSUE_B2(kt, buf) _Pragma("unroll") for (int it = 0; it < 2; ++it) {      \
    int flat = (it * 1024 + t) * 8;                                               \
    int n = flat >> 6, k = flat & 63;                                             \
    const unsigned short* g = W2t + n * 256 + (kt) * 64 + (k ^ ((n & 7) << 3));   \
    __builtin_amdgcn_global_load_lds(                                             \
        (const __attribute__((address_space(1))) unsigned int*)g,                 \
        (__attribute__((address_space(3))) unsigned int*)                         \
            &sB2[(buf) * 16384 + (it * 16 + wave) * 512], 16, 0, 0); }

  ISSUE_B2(0, 0);
  __syncthreads();
  for (int kt = 0; kt < 4; ++kt) {
    const int cur = kt & 1, nxt = cur ^ 1;
    if (kt + 1 < 4) ISSUE_B2(kt + 1, nxt);
#pragma unroll
    for (int kk = 0; kk < 2; ++kk) {
      const int kb = kk * 32 + (lane >> 4) * 8;
      bf16x8 af[2], bfr[4];
#pragma unroll
      for (int m = 0; m < 2; ++m) {
        int r = wr * 32 + m * 16 + (lane & 15);
        int col = kt * 64 + kb;
        af[m] = *(const bf16x8*)&G1L[r * 256 + (col ^ ((r & 7) << 3))];
      }
#pragma unroll
      for (int n = 0; n < 4; ++n) {
        int r = wc * 64 + n * 16 + (lane & 15);
        bfr[n] = *(const bf16x8*)&sB2[cur * 16384 + r * 64 + (kb ^ ((r & 7) << 3))];
      }
#pragma unroll
      for (int m = 0; m < 2; ++m)
#pragma unroll
        for (int n = 0; n < 4; ++n)
          acc[m][n] = __builtin_amdgcn_mfma_f32_16x16x32_bf16(af[m], bfr[n], acc[m][n], 0, 0, 0);
    }
    __syncthreads();
  }
  // acc -> H2 (bf16, over dead sB2)
#pragma unroll
  for (int m = 0; m < 2; ++m)
#pragma unroll
    for (int n = 0; n < 4; ++n) {
      int r = wr * 32 + m * 16 + (lane >> 4) * 4;
      int c = wc * 64 + n * 16 + (lane & 15);
#pragma unroll
      for (int j = 0; j < 4; ++j) H2[(r + j) * 256 + c] = f2bf(acc[m][n][j]);
    }
  __syncthreads();
  // stencil2 + b2 -> hB (over dead G1L); it<8 covers ALL 128 lines
#pragma unroll
  for (int it = 0; it < 8; ++it) {
    int g = it * 1024 + t;
    int l = g >> 6, c0 = (g & 63) * 4;
    int dl = degf(l);
    f32x4 s = (f32x4)0.0f;
#pragma unroll
    for (int o = -2; o <= 2; ++o) {
      int q = l + o;
      if (q < 0 || q > 127) continue;
      float w = __frsqrt_rn((float)(dl * degf(q)));
      bf16x4 hv4 = *(const bf16x4*)&H2[q * 256 + c0];
      f32x4 hv; cvt4dot(hv4, &hv);
      s += w * hv;
    }
    f32x4 b = *(const f32x4*)&b2[c0];
    unsigned short o4[4];
#pragma unroll
    for (int j = 0; j < 4; ++j) o4[j] = f2bf(s[j] + b[j]);
    *(bf16x4*)&hB[l * 256 + c0] = *(bf16x4*)o4;
  }
  __syncthreads();

  // ======================= attention pooling ===============================
  {  // logits: 8 lanes per line, rotated channel order
    int l = t >> 3, p = t & 7;
    float part = 0.f;
#pragma unroll 4
    for (int j = 0; j < 32; ++j) {
      int c = p * 32 + ((j + 4 * p + l) & 31);
      part += bf2f(hB[l * 256 + c]) * awS[c];
    }
    part += __shfl_xor(part, 1);
    part += __shfl_xor(part, 2);
    part += __shfl_xor(part, 4);
    if (p == 0) lgS[l] = part + attn_b[0];
  }
  __syncthreads();
  if (t < 64) redM[t] = fmaxf(lgS[t], lgS[t + 64]);
  __syncthreads();
  for (int s = 32; s > 0; s >>= 1) {
    if (t < s) redM[t] = fmaxf(redM[t], redM[t + s]);
    __syncthreads();
  }
  float mx = redM[0];
  __syncthreads();
  if (t < 128) lgS[t] = expf(lgS[t] - mx);
  __syncthreads();
  if (t < 64) redM[t] = lgS[t] + lgS[t + 64];
  __syncthreads();
  for (int s = 32; s > 0; s >>= 1) {
    if (t < s) redM[t] += redM[t + s];
    __syncthreads();
  }
  float dn = redM[0];
  __syncthreads();
  if (t < 128) {
    float w = lgS[t] / dn;
    lgS[t] = w;
    out[131584 + file * 128 + t] = w;
  }
  __syncthreads();
  {  // h_file[c] = sum_l w[l]*h[l][c]
    int c = t & 255, grp = t >> 8;
    float s = 0.f;
    for (int l = grp * 32; l < grp * 32 + 32; ++l) s += lgS[l] * bf2f(hB[l * 256 + c]);
    scr[grp * 256 + c] = s;
  }
  __syncthreads();
  if (t < 256) {
    float tot = scr[t] + scr[256 + t] + scr[512 + t] + scr[768 + t];
    hfS[t] = tot;
    out[512 + file * 256 + t] = tot;
  }
  __syncthreads();

  // ======================= heads ===========================================
  {  // z_shared / z_private partials: 4 c-groups x 128 outputs each
    if (t < 512) {
      int g = t >> 7, j = t & 127;
      float s = 0.f;
      for (int c = g * 64; c < g * 64 + 64; ++c) s += hfS[c] * Ws[c * 128 + j];
      scr[g * 128 + j] = s;
    } else {
      int tt = t - 512, g = tt >> 7, j = tt & 127;
      float s = 0.f;
      for (int c = g * 64; c < g * 64 + 64; ++c) s += hfS[c] * Wp[c * 128 + j];
      scr[512 + g * 128 + j] = s;
    }
  }
  __syncthreads();
  {
    int j = t & 127;
    if (t < 128) {
      float zs = bs[j] + scr[j] + scr[128 + j] + scr[256 + j] + scr[384 + j];
      zsS[j] = zs;
      out[66048 + file * 128 + j] = zs;
      float s = wsum(zs * zs);
      if (lane == 0) redS[wave] = s;           // waves 0,1
    } else if (t < 256) {
      float zp = bp[j] + scr[512 + j] + scr[640 + j] + scr[768 + j] + scr[896 + j];
      out[98816 + file * 128 + j] = zp;
    }
  }
  __syncthreads();
  if (t == 0) redS[8] = fmaxf(sqrtf(redS[0] + redS[1]), 1e-12f);
  __syncthreads();
  if (t < 128) znS[t] = zsS[t] / redS[8];
  __syncthreads();
  {  // AM-softmax: dot(zsn, cls_w[:,k]) and ||cls_w[:,k]||
    int j = t & 127;
    if (t < 512) {
      float v;
      if (t < 128)       v = znS[j] * cls_w[j * 2 + 0];
      else if (t < 256)  v = znS[j] * cls_w[j * 2 + 1];
      else if (t < 384)  { float w0 = cls_w[j * 2 + 0]; v = w0 * w0; }
      else               { float w1 = cls_w[j * 2 + 1]; v = w1 * w1; }
      float s = wsum(v);
      if (lane == 0) redS[wave] = s;           // waves 0..7
    }
  }
  __syncthreads();
  if (t == 0) {
    float d0 = redS[0] + redS[1], d1 = redS[2] + redS[3];
    float n0 = fmaxf(sqrtf(redS[4] + redS[5]), 1e-12f);
    float n1 = fmaxf(sqrtf(redS[6] + redS[7]), 1e-12f);
    int lab = labels[file];
    out[file * 2 + 0] = 30.0f * (d0 / n0 - 0.35f * (lab == 0 ? 1.f : 0.f));
    out[file * 2 + 1] = 30.0f * (d1 / n1 - 0.35f * (lab == 1 ? 1.f : 0.f));
  }
  __syncthreads();
  {  // domain head
    int j = t & 127;
    if (t < 128) {
      float dd = bd1[j];
      for (int a = 0; a < 128; ++a) dd += zsS[a] * Wd1[a * 128 + j];
      dd = fmaxf(dd, 0.f);
      float s0 = wsum(dd * Wd2[j * 2 + 0]);
      if (lane == 0) redS[wave] = s0;          // waves 0,1
      float s1 = wsum(dd * Wd2[j * 2 + 1]);
      if (lane == 0) redS[4 + wave] = s1;
    }
  }
  __syncthreads();
  if (t == 0) {
    out[164352 + file * 2 + 0] = redS[0] + redS[1] + bd2[0];
    out[164352 + file * 2 + 1] = redS[4] + redS[5] + bd2[1];
  }
#undef ISSUE_A1
#undef WRITE_A1
#undef ISSUE_B1
#undef ISSUE_B2
}

// ------- znorm: zsn/zpn from validated z_shared/z_private in d_out --------
__global__ __launch_bounds__(128) void znorm(const float* __restrict__ out,
                                             float* __restrict__ zsn,
                                             float* __restrict__ zpn) {
  const int f = blockIdx.x, j = threadIdx.x;
  __shared__ float red[128];
  float zs = out[66048 + f * 128 + j];
  float zp = out[98816 + f * 128 + j];
  red[j] = zs * zs; __syncthreads();
  for (int s = 64; s > 0; s >>= 1) { if (j < s) red[j] += red[j + s]; __syncthreads(); }
  float ns = sqrtf(red[0]); __syncthreads();
  zsn[f * 128 + j] = zs / fmaxf(ns, 1e-12f);
  red[j] = zp * zp; __syncthreads();
  for (int s = 64; s > 0; s >>= 1) { if (j < s) red[j] += red[j + s]; __syncthreads(); }
  float np = sqrtf(red[0]); __syncthreads();
  zpn[f * 128 + j] = zp / fmaxf(np, 1e-12f);
}

// ---------------- ortho: ||zsn^T @ zpn||_F --------------------------------
__global__ __launch_bounds__(128) void ortho_partial(const float* __restrict__ zsn,
                                                     const float* __restrict__ zpn,
                                                     float* __restrict__ partial) {
  const int a = blockIdx.x, b = threadIdx.x;
  float s = 0.f;
  for (int f = 0; f < 256; ++f) s += zsn[f * 128 + a] * zpn[f * 128 + b];
  __shared__ float red[128];
  red[b] = s * s; __syncthreads();
  for (int st = 64; st > 0; st >>= 1) { if (b < st) red[b] += red[b + st]; __syncthreads(); }
  if (b == 0) partial[a] = red[0];
}

__global__ __launch_bounds__(128) void ortho_final(const float* __restrict__ partial,
                                                   float* __restrict__ out) {
  const int t = threadIdx.x;
  __shared__ float red[128];
  red[t] = partial[t]; __syncthreads();
  for (int st = 64; st > 0; st >>= 1) { if (t < st) red[t] += red[t + st]; __syncthreads(); }
  if (t == 0) out[164864] = sqrtf(red[0]);
}

extern "C" void kernel_launch(void* const* d_in, const int* in_sizes, int n_in,
                              void* d_out, int out_size, void* d_ws, size_t ws_size,
                              hipStream_t stream) {
  const float* line_emb = (const float*)d_in[0];
  const float* W1     = (const float*)d_in[1];
  const float* b1     = (const float*)d_in[2];
  const float* W2     = (const float*)d_in[3];
  const float* b2     = (const float*)d_in[4];
  const float* attn_w = (const float*)d_in[5];
  const float* attn_b = (const float*)d_in[6];
  const float* Ws     = (const float*)d_in[7];
  const float* bs     = (const float*)d_in[8];
  const float* Wp     = (const float*)d_in[9];
  const float* bp     = (const float*)d_in[10];
  const float* cls_w  = (const float*)d_in[11];
  const float* Wd1    = (const float*)d_in[12];
  const float* bd1    = (const float*)d_in[13];
  const float* Wd2    = (const float*)d_in[14];
  const float* bd2    = (const float*)d_in[15];
  const int* labels   = (const int*)d_in[18];

  char* ws = (char*)d_ws;
  unsigned short* W1t = (unsigned short*)(ws + 0);        // [256][768] bf16
  unsigned short* W2t = (unsigned short*)(ws + 393216);   // [256][256] bf16
  float* zsn          = (float*)(ws + 524288);            // [256][128] f32
  float* zpn          = (float*)(ws + 655360);            // [256][128] f32
  float* partial      = (float*)(ws + 786432);            // 128 f32
  float* out          = (float*)d_out;

  prep_weights<<<dim3(256), dim3(32, 8), 0, stream>>>(W1, W2, W1t, W2t);
  mega<<<dim3(256), dim3(1024), 0, stream>>>(line_emb, W1t, b1, W2t, b2,
                                             attn_w, attn_b, Ws, bs, Wp, bp,
                                             cls_w, labels, Wd1, bd1, Wd2, bd2, out);
  znorm<<<dim3(256), dim3(128), 0, stream>>>(out, zsn, zpn);
  ortho_partial<<<dim3(128), dim3(128), 0, stream>>>(zsn, zpn, partial);
  ortho_final<<<dim3(1), dim3(128), 0, stream>>>(partial, out);
}

// Round 9
// 73.751 us; speedup vs baseline: 2.6648x; 1.0133x over previous
//
#include <hip/hip_runtime.h>

// GraphCodeBertCPDP forward on MI355X (gfx950) — round 9.
// vs round 8: both K-loops now use counted s_waitcnt vmcnt(N) + RAW s_barrier
// (no per-iter vmcnt(0) drain). A is staged as f32 via global_load_lds with a
// pre-swizzled SOURCE (linear LDS dest), cvt to bf16 at fragment read — so all
// in-loop vmcnt events are explicit DMAs (deterministic counting). Full
// __syncthreads() drain before each loop isolates compiler-hoisted loads.
// Domain-head GEMV split 4x. Everything else identical to round 8 (passed).
// Output layout (f32): [0:512) logits_cls | [512:66048) h_file |
//   [66048:98816) z_shared | [98816:131584) z_private | [131584:164352) att_w
//   [164352:164864) domain_logits | [164864] ortho

typedef __attribute__((ext_vector_type(8))) short bf16x8;
typedef __attribute__((ext_vector_type(4))) short bf16x4;
typedef __attribute__((ext_vector_type(4))) float f32x4;
typedef __attribute__((ext_vector_type(8))) float f32x8;

__device__ __forceinline__ unsigned short f2bf(float f) {
  union { float f; unsigned int i; } v; v.f = f;
  unsigned int r = v.i + 0x7FFFu + ((v.i >> 16) & 1u);
  return (unsigned short)(r >> 16);
}
__device__ __forceinline__ float bf2f(unsigned short u) {
  union { unsigned int i; float f; } v; v.i = ((unsigned int)u) << 16; return v.f;
}
__device__ __forceinline__ bf16x8 cvt8(f32x8 v) {
  unsigned short u[8];
#pragma unroll
  for (int j = 0; j < 8; ++j) u[j] = f2bf(v[j]);
  return *(bf16x8*)u;
}
__device__ __forceinline__ float cvt4dot(bf16x4 v, f32x4* o) {
  (*o)[0] = bf2f(((unsigned short*)&v)[0]); (*o)[1] = bf2f(((unsigned short*)&v)[1]);
  (*o)[2] = bf2f(((unsigned short*)&v)[2]); (*o)[3] = bf2f(((unsigned short*)&v)[3]);
  return 0.f;
}
__device__ __forceinline__ int degf(int p) {  // degree+1 (self-loop)
  return 5 - (p < 2 ? 2 - p : 0) - (p > 125 ? p - 125 : 0);
}
__device__ __forceinline__ float wsum(float v) {
#pragma unroll
  for (int o = 1; o < 64; o <<= 1) v += __shfl_xor(v, o);
  return v;
}

// ---------- merged tiled convert+transpose for W1 and W2 ------------------
__global__ void prep_weights(const float* __restrict__ W1, const float* __restrict__ W2,
                             unsigned short* __restrict__ W1t, unsigned short* __restrict__ W2t) {
  __shared__ float tile[32][33];
  int id = blockIdx.x;
  const float* src; unsigned short* dst; int R, C, bx, by;
  if (id < 192) { src = W1; dst = W1t; R = 768; C = 256; bx = (id % 8) * 32; by = (id / 8) * 32; }
  else { id -= 192; src = W2; dst = W2t; R = 256; C = 256; bx = (id % 8) * 32; by = (id / 8) * 32; }
  int tx = threadIdx.x, ty = threadIdx.y;  // 32 x 8
#pragma unroll
  for (int j = 0; j < 32; j += 8)
    tile[ty + j][tx] = src[(by + ty + j) * C + bx + tx];
  __syncthreads();
#pragma unroll
  for (int j = 0; j < 32; j += 8)
    dst[(bx + ty + j) * R + by + tx] = f2bf(tile[tx][ty + j]);
}

// --------------------------- megakernel -----------------------------------
__global__ __launch_bounds__(1024) void mega(const float* __restrict__ A,
    const unsigned short* __restrict__ W1t, const float* __restrict__ b1,
    const unsigned short* __restrict__ W2t, const float* __restrict__ b2,
    const float* __restrict__ attn_w, const float* __restrict__ attn_b,
    const float* __restrict__ Ws, const float* __restrict__ bs,
    const float* __restrict__ Wp, const float* __restrict__ bp,
    const float* __restrict__ cls_w, const int* __restrict__ labels,
    const float* __restrict__ Wd1, const float* __restrict__ bd1,
    const float* __restrict__ Wd2, const float* __restrict__ bd2,
    float* __restrict__ out) {
  __shared__ __align__(16) char lds[131072];
  // phase1 staging: A as f32 (cvt at frag read), B as bf16
  float*          sAf = (float*)lds;                    // [2][128][64] f32, 64 KB @ [0,64K)
  unsigned short* sB1 = (unsigned short*)(lds + 65536); // [2][256][64] bf16, 64 KB @ [64K,128K)
  // post-phase1 overlays
  unsigned short* H1  = (unsigned short*)lds;            // [128][256] bf16 @ [0,64K) (over sAf)
  unsigned short* G1L = (unsigned short*)(lds + 65536);  // [128][256] bf16 swz @ [64K,128K)
  // phase2 overlays
  unsigned short* sB2 = (unsigned short*)lds;            // [2][256][64] bf16 @ [0,64K) (over H1)
  unsigned short* H2  = (unsigned short*)lds;            // [128][256] bf16 @ [0,64K) (after loop2)
  unsigned short* hB  = (unsigned short*)(lds + 65536);  // [128][256] bf16 @ [64K,128K) (over G1L)
  __shared__ float awS[256];
  __shared__ float lgS[128];
  __shared__ float redM[64];
  __shared__ float scr[1024];
  __shared__ float hfS[256];
  __shared__ float zsS[128], znS[128];
  __shared__ float redS[16];

  const int t = threadIdx.x;
  const int wave = t >> 6, lane = t & 63;
  const int wr = wave >> 2, wc = wave & 3;              // 4x4 waves, 32x64 tiles
  const int file = blockIdx.x;
  const long rowA = (long)file * 128;

  if (t < 256) awS[t] = attn_w[t];   // drained by the pre-loop __syncthreads

  f32x4 acc[2][4];
#pragma unroll
  for (int m = 0; m < 2; ++m)
#pragma unroll
    for (int n = 0; n < 4; ++n) acc[m][n] = (f32x4)0.0f;

  // ======================= phase 1: H1 = A @ W1t^T =========================
  // A stage: pure DMA, f32, source pre-swizzled (k ^= (r&7)<<3 on f32 idx),
  // linear LDS dest. 2 gld_lds/thread = 2 vmcnt events.
#define ISSUE_A1(kt, buf) _Pragma("unroll") for (int it = 0; it < 2; ++it) {      \
    int flat = (it * 1024 + t) * 4;  /* f32 elem idx in [128][64] tile */         \
    int r = flat >> 6, k = flat & 63;                                             \
    const float* g = A + (rowA + r) * 768 + (kt) * 64 + (k ^ ((r & 7) << 3));     \
    __builtin_amdgcn_global_load_lds(                                             \
        (const __attribute__((address_space(1))) unsigned int*)g,                 \
        (__attribute__((address_space(3))) unsigned int*)                         \
            &sAf[(buf) * 8192 + (it * 16 + wave) * 256], 16, 0, 0); }
  // B stage: bf16, source pre-swizzled, linear dest. 2 events.
#define ISSUE_B1(kt, buf) _Pragma("unroll") for (int it = 0; it < 2; ++it) {      \
    int flat = (it * 1024 + t) * 8;                                               \
    int n = flat >> 6, k = flat & 63;                                             \
    const unsigned short* g = W1t + n * 768 + (kt) * 64 + (k ^ ((n & 7) << 3));   \
    __builtin_amdgcn_global_load_lds(                                             \
        (const __attribute__((address_space(1))) unsigned int*)g,                 \
        (__attribute__((address_space(3))) unsigned int*)                         \
            &sB1[(buf) * 16384 + (it * 16 + wave) * 512], 16, 0, 0); }

  ISSUE_A1(0, 0); ISSUE_B1(0, 0);
  __syncthreads();   // full drain: stage 0 landed, hoisted scalar loads retired
  for (int kt = 0; kt < 12; ++kt) {
    const int cur = kt & 1, nxt = cur ^ 1;
    if (kt + 1 < 12) {
      ISSUE_A1(kt + 1, nxt); ISSUE_B1(kt + 1, nxt);
      // 4 events in flight (stage kt+1); force stage kt retired
      asm volatile("s_waitcnt vmcnt(4)" ::: "memory");
    } else {
      asm volatile("s_waitcnt vmcnt(0)" ::: "memory");
    }
    __builtin_amdgcn_sched_barrier(0);
#pragma unroll
    for (int kk = 0; kk < 2; ++kk) {
      const int kb = kk * 32 + (lane >> 4) * 8;
      bf16x8 af[2], bfr[4];
#pragma unroll
      for (int m = 0; m < 2; ++m) {
        int r = wr * 32 + m * 16 + (lane & 15);
        f32x8 a8 = *(const f32x8*)&sAf[cur * 8192 + r * 64 + (kb ^ ((r & 7) << 3))];
        af[m] = cvt8(a8);
      }
#pragma unroll
      for (int n = 0; n < 4; ++n) {
        int r = wc * 64 + n * 16 + (lane & 15);
        bfr[n] = *(const bf16x8*)&sB1[cur * 16384 + r * 64 + (kb ^ ((r & 7) << 3))];
      }
#pragma unroll
      for (int m = 0; m < 2; ++m)
#pragma unroll
        for (int n = 0; n < 4; ++n)
          acc[m][n] = __builtin_amdgcn_mfma_f32_16x16x32_bf16(af[m], bfr[n], acc[m][n], 0, 0, 0);
    }
    __builtin_amdgcn_sched_barrier(0);  // nothing crosses the raw barrier
    __builtin_amdgcn_s_barrier();
  }
  // acc -> H1 (bf16).  C/D layout: col = lane&15, row = (lane>>4)*4+j
#pragma unroll
  for (int m = 0; m < 2; ++m)
#pragma unroll
    for (int n = 0; n < 4; ++n) {
      int r = wr * 32 + m * 16 + (lane >> 4) * 4;
      int c = wc * 64 + n * 16 + (lane & 15);
#pragma unroll
      for (int j = 0; j < 4; ++j) H1[(r + j) * 256 + c] = f2bf(acc[m][n][j]);
    }
  __syncthreads();
  // stencil1 + b1 + relu -> G1L (swizzled cols); it<8 covers ALL 128 lines
#pragma unroll
  for (int it = 0; it < 8; ++it) {
    int g = it * 1024 + t;
    int l = g >> 6, c0 = (g & 63) * 4;
    int dl = degf(l);
    f32x4 s = (f32x4)0.0f;
#pragma unroll
    for (int o = -2; o <= 2; ++o) {
      int q = l + o;
      if (q < 0 || q > 127) continue;
      float w = __frsqrt_rn((float)(dl * degf(q)));
      bf16x4 hv4 = *(const bf16x4*)&H1[q * 256 + c0];
      f32x4 hv; cvt4dot(hv4, &hv);
      s += w * hv;
    }
    f32x4 b = *(const f32x4*)&b1[c0];
    unsigned short o4[4];
#pragma unroll
    for (int j = 0; j < 4; ++j) o4[j] = f2bf(fmaxf(s[j] + b[j], 0.f));
    *(bf16x4*)&G1L[l * 256 + (c0 ^ ((l & 7) << 3))] = *(bf16x4*)o4;
  }
  __syncthreads();

  // ======================= phase 2: H2 = G1 @ W2t^T ========================
#pragma unroll
  for (int m = 0; m < 2; ++m)
#pragma unroll
    for (int n = 0; n < 4; ++n) acc[m][n] = (f32x4)0.0f;
#define ISSUE_B2(kt, buf) _Pragma("unroll") for (int it = 0; it < 2; ++it) {      \
    int flat = (it * 1024 + t) * 8;                                               \
    int n = flat >> 6, k = flat & 63;                                             \
    const unsigned short* g = W2t + n * 256 + (kt) * 64 + (k ^ ((n & 7) << 3));   \
    __builtin_amdgcn_global_load_lds(                                             \
        (const __attribute__((address_space(1))) unsigned int*)g,                 \
        (__attribute__((address_space(3))) unsigned int*)                         \
            &sB2[(buf) * 16384 + (it * 16 + wave) * 512], 16, 0, 0); }

  ISSUE_B2(0, 0);
  __syncthreads();   // drain
  for (int kt = 0; kt < 4; ++kt) {
    const int cur = kt & 1, nxt = cur ^ 1;
    if (kt + 1 < 4) {
      ISSUE_B2(kt + 1, nxt);
      asm volatile("s_waitcnt vmcnt(2)" ::: "memory");
    } else {
      asm volatile("s_waitcnt vmcnt(0)" ::: "memory");
    }
    __builtin_amdgcn_sched_barrier(0);
#pragma unroll
    for (int kk = 0; kk < 2; ++kk) {
      const int kb = kk * 32 + (lane >> 4) * 8;
      bf16x8 af[2], bfr[4];
#pragma unroll
      for (int m = 0; m < 2; ++m) {
        int r = wr * 32 + m * 16 + (lane & 15);
        int col = kt * 64 + kb;
        af[m] = *(const bf16x8*)&G1L[r * 256 + (col ^ ((r & 7) << 3))];
      }
#pragma unroll
      for (int n = 0; n < 4; ++n) {
        int r = wc * 64 + n * 16 + (lane & 15);
        bfr[n] = *(const bf16x8*)&sB2[cur * 16384 + r * 64 + (kb ^ ((r & 7) << 3))];
      }
#pragma unroll
      for (int m = 0; m < 2; ++m)
#pragma unroll
        for (int n = 0; n < 4; ++n)
          acc[m][n] = __builtin_amdgcn_mfma_f32_16x16x32_bf16(af[m], bfr[n], acc[m][n], 0, 0, 0);
    }
    __builtin_amdgcn_sched_barrier(0);
    __builtin_amdgcn_s_barrier();
  }
  // acc -> H2 (bf16, over dead sB2)
#pragma unroll
  for (int m = 0; m < 2; ++m)
#pragma unroll
    for (int n = 0; n < 4; ++n) {
      int r = wr * 32 + m * 16 + (lane >> 4) * 4;
      int c = wc * 64 + n * 16 + (lane & 15);
#pragma unroll
      for (int j = 0; j < 4; ++j) H2[(r + j) * 256 + c] = f2bf(acc[m][n][j]);
    }
  __syncthreads();
  // stencil2 + b2 -> hB (over dead G1L); it<8 covers ALL 128 lines
#pragma unroll
  for (int it = 0; it < 8; ++it) {
    int g = it * 1024 + t;
    int l = g >> 6, c0 = (g & 63) * 4;
    int dl = degf(l);
    f32x4 s = (f32x4)0.0f;
#pragma unroll
    for (int o = -2; o <= 2; ++o) {
      int q = l + o;
      if (q < 0 || q > 127) continue;
      float w = __frsqrt_rn((float)(dl * degf(q)));
      bf16x4 hv4 = *(const bf16x4*)&H2[q * 256 + c0];
      f32x4 hv; cvt4dot(hv4, &hv);
      s += w * hv;
    }
    f32x4 b = *(const f32x4*)&b2[c0];
    unsigned short o4[4];
#pragma unroll
    for (int j = 0; j < 4; ++j) o4[j] = f2bf(s[j] + b[j]);
    *(bf16x4*)&hB[l * 256 + c0] = *(bf16x4*)o4;
  }
  __syncthreads();

  // ======================= attention pooling ===============================
  {  // logits: 8 lanes per line, rotated channel order
    int l = t >> 3, p = t & 7;
    float part = 0.f;
#pragma unroll 4
    for (int j = 0; j < 32; ++j) {
      int c = p * 32 + ((j + 4 * p + l) & 31);
      part += bf2f(hB[l * 256 + c]) * awS[c];
    }
    part += __shfl_xor(part, 1);
    part += __shfl_xor(part, 2);
    part += __shfl_xor(part, 4);
    if (p == 0) lgS[l] = part + attn_b[0];
  }
  __syncthreads();
  if (t < 64) redM[t] = fmaxf(lgS[t], lgS[t + 64]);
  __syncthreads();
  for (int s = 32; s > 0; s >>= 1) {
    if (t < s) redM[t] = fmaxf(redM[t], redM[t + s]);
    __syncthreads();
  }
  float mx = redM[0];
  __syncthreads();
  if (t < 128) lgS[t] = expf(lgS[t] - mx);
  __syncthreads();
  if (t < 64) redM[t] = lgS[t] + lgS[t + 64];
  __syncthreads();
  for (int s = 32; s > 0; s >>= 1) {
    if (t < s) redM[t] += redM[t + s];
    __syncthreads();
  }
  float dn = redM[0];
  __syncthreads();
  if (t < 128) {
    float w = lgS[t] / dn;
    lgS[t] = w;
    out[131584 + file * 128 + t] = w;
  }
  __syncthreads();
  {  // h_file[c] = sum_l w[l]*h[l][c]
    int c = t & 255, grp = t >> 8;
    float s = 0.f;
    for (int l = grp * 32; l < grp * 32 + 32; ++l) s += lgS[l] * bf2f(hB[l * 256 + c]);
    scr[grp * 256 + c] = s;
  }
  __syncthreads();
  if (t < 256) {
    float tot = scr[t] + scr[256 + t] + scr[512 + t] + scr[768 + t];
    hfS[t] = tot;
    out[512 + file * 256 + t] = tot;
  }
  __syncthreads();

  // ======================= heads ===========================================
  {  // z_shared / z_private partials: 4 c-groups x 128 outputs each
    if (t < 512) {
      int g = t >> 7, j = t & 127;
      float s = 0.f;
      for (int c = g * 64; c < g * 64 + 64; ++c) s += hfS[c] * Ws[c * 128 + j];
      scr[g * 128 + j] = s;
    } else {
      int tt = t - 512, g = tt >> 7, j = tt & 127;
      float s = 0.f;
      for (int c = g * 64; c < g * 64 + 64; ++c) s += hfS[c] * Wp[c * 128 + j];
      scr[512 + g * 128 + j] = s;
    }
  }
  __syncthreads();
  {
    int j = t & 127;
    if (t < 128) {
      float zs = bs[j] + scr[j] + scr[128 + j] + scr[256 + j] + scr[384 + j];
      zsS[j] = zs;
      out[66048 + file * 128 + j] = zs;
      float s = wsum(zs * zs);
      if (lane == 0) redS[wave] = s;           // waves 0,1
    } else if (t < 256) {
      float zp = bp[j] + scr[512 + j] + scr[640 + j] + scr[768 + j] + scr[896 + j];
      out[98816 + file * 128 + j] = zp;
    }
  }
  __syncthreads();
  if (t == 0) redS[8] = fmaxf(sqrtf(redS[0] + redS[1]), 1e-12f);
  __syncthreads();
  if (t < 128) znS[t] = zsS[t] / redS[8];
  __syncthreads();
  {  // AM-softmax: dot(zsn, cls_w[:,k]) and ||cls_w[:,k]||
    int j = t & 127;
    if (t < 512) {
      float v;
      if (t < 128)       v = znS[j] * cls_w[j * 2 + 0];
      else if (t < 256)  v = znS[j] * cls_w[j * 2 + 1];
      else if (t < 384)  { float w0 = cls_w[j * 2 + 0]; v = w0 * w0; }
      else               { float w1 = cls_w[j * 2 + 1]; v = w1 * w1; }
      float s = wsum(v);
      if (lane == 0) redS[wave] = s;           // waves 0..7
    }
  }
  __syncthreads();
  if (t == 0) {
    float d0 = redS[0] + redS[1], d1 = redS[2] + redS[3];
    float n0 = fmaxf(sqrtf(redS[4] + redS[5]), 1e-12f);
    float n1 = fmaxf(sqrtf(redS[6] + redS[7]), 1e-12f);
    int lab = labels[file];
    out[file * 2 + 0] = 30.0f * (d0 / n0 - 0.35f * (lab == 0 ? 1.f : 0.f));
    out[file * 2 + 1] = 30.0f * (d1 / n1 - 0.35f * (lab == 1 ? 1.f : 0.f));
  }
  __syncthreads();
  {  // domain head: a-sum split 4x across 512 threads
    if (t < 512) {
      int g = t >> 7, j = t & 127;
      float s = 0.f;
      for (int a = g * 32; a < g * 32 + 32; ++a) s += zsS[a] * Wd1[a * 128 + j];
      scr[g * 128 + j] = s;
    }
  }
  __syncthreads();
  {
    int j = t & 127;
    if (t < 128) {
      float dd = fmaxf(bd1[j] + scr[j] + scr[128 + j] + scr[256 + j] + scr[384 + j], 0.f);
      float s0 = wsum(dd * Wd2[j * 2 + 0]);
      if (lane == 0) redS[wave] = s0;          // waves 0,1
      float s1 = wsum(dd * Wd2[j * 2 + 1]);
      if (lane == 0) redS[4 + wave] = s1;
    }
  }
  __syncthreads();
  if (t == 0) {
    out[164352 + file * 2 + 0] = redS[0] + redS[1] + bd2[0];
    out[164352 + file * 2 + 1] = redS[4] + redS[5] + bd2[1];
  }
#undef ISSUE_A1
#undef ISSUE_B1
#undef ISSUE_B2
}

// ------- znorm: zsn/zpn from validated z_shared/z_private in d_out --------
__global__ __launch_bounds__(128) void znorm(const float* __restrict__ out,
                                             float* __restrict__ zsn,
                                             float* __restrict__ zpn) {
  const int f = blockIdx.x, j = threadIdx.x;
  __shared__ float red[128];
  float zs = out[66048 + f * 128 + j];
  float zp = out[98816 + f * 128 + j];
  red[j] = zs * zs; __syncthreads();
  for (int s = 64; s > 0; s >>= 1) { if (j < s) red[j] += red[j + s]; __syncthreads(); }
  float ns = sqrtf(red[0]); __syncthreads();
  zsn[f * 128 + j] = zs / fmaxf(ns, 1e-12f);
  red[j] = zp * zp; __syncthreads();
  for (int s = 64; s > 0; s >>= 1) { if (j < s) red[j] += red[j + s]; __syncthreads(); }
  float np = sqrtf(red[0]); __syncthreads();
  zpn[f * 128 + j] = zp / fmaxf(np, 1e-12f);
}

// ---------------- ortho: ||zsn^T @ zpn||_F --------------------------------
__global__ __launch_bounds__(128) void ortho_partial(const float* __restrict__ zsn,
                                                     const float* __restrict__ zpn,
                                                     float* __restrict__ partial) {
  const int a = blockIdx.x, b = threadIdx.x;
  float s = 0.f;
  for (int f = 0; f < 256; ++f) s += zsn[f * 128 + a] * zpn[f * 128 + b];
  __shared__ float red[128];
  red[b] = s * s; __syncthreads();
  for (int st = 64; st > 0; st >>= 1) { if (b < st) red[b] += red[b + st]; __syncthreads(); }
  if (b == 0) partial[a] = red[0];
}

__global__ __launch_bounds__(128) void ortho_final(const float* __restrict__ partial,
                                                   float* __restrict__ out) {
  const int t = threadIdx.x;
  __shared__ float red[128];
  red[t] = partial[t]; __syncthreads();
  for (int st = 64; st > 0; st >>= 1) { if (t < st) red[t] += red[t + st]; __syncthreads(); }
  if (t == 0) out[164864] = sqrtf(red[0]);
}

extern "C" void kernel_launch(void* const* d_in, const int* in_sizes, int n_in,
                              void* d_out, int out_size, void* d_ws, size_t ws_size,
                              hipStream_t stream) {
  const float* line_emb = (const float*)d_in[0];
  const float* W1     = (const float*)d_in[1];
  const float* b1     = (const float*)d_in[2];
  const float* W2     = (const float*)d_in[3];
  const float* b2     = (const float*)d_in[4];
  const float* attn_w = (const float*)d_in[5];
  const float* attn_b = (const float*)d_in[6];
  const float* Ws     = (const float*)d_in[7];
  const float* bs     = (const float*)d_in[8];
  const float* Wp     = (const float*)d_in[9];
  const float* bp     = (const float*)d_in[10];
  const float* cls_w  = (const float*)d_in[11];
  const float* Wd1    = (const float*)d_in[12];
  const float* bd1    = (const float*)d_in[13];
  const float* Wd2    = (const float*)d_in[14];
  const float* bd2    = (const float*)d_in[15];
  const int* labels   = (const int*)d_in[18];

  char* ws = (char*)d_ws;
  unsigned short* W1t = (unsigned short*)(ws + 0);        // [256][768] bf16
  unsigned short* W2t = (unsigned short*)(ws + 393216);   // [256][256] bf16
  float* zsn          = (float*)(ws + 524288);            // [256][128] f32
  float* zpn          = (float*)(ws + 655360);            // [256][128] f32
  float* partial      = (float*)(ws + 786432);            // 128 f32
  float* out          = (float*)d_out;

  prep_weights<<<dim3(256), dim3(32, 8), 0, stream>>>(W1, W2, W1t, W2t);
  mega<<<dim3(256), dim3(1024), 0, stream>>>(line_emb, W1t, b1, W2t, b2,
                                             attn_w, attn_b, Ws, bs, Wp, bp,
                                             cls_w, labels, Wd1, bd1, Wd2, bd2, out);
  znorm<<<dim3(256), dim3(128), 0, stream>>>(out, zsn, zpn);
  ortho_partial<<<dim3(128), dim3(128), 0, stream>>>(zsn, zpn, partial);
  ortho_final<<<dim3(1), dim3(128), 0, stream>>>(partial, out);
}

// Round 10
// 73.183 us; speedup vs baseline: 2.6855x; 1.0078x over previous
//
#include <hip/hip_runtime.h>

// GraphCodeBertCPDP forward on MI355X (gfx950) — round 10.
// vs round 9: (a) A-staging reverted to round-8 reg-stage+cvt-once (round 9's
// f32-LDS path cost 4x redundant cvt: VALU 17->23%, conflicts 1.05M->2.62M);
// (b) head GEMV weights (Ws/Wp/Wd1) pre-converted to bf16 by prep_weights and
// DMA-staged into LDS regions that die after stencil2/pooling, ping-ponged:
//   WSB -> [0,64K)  issued after stencil2 (H2 dead), consumed by s-GEMV
//   WPB -> [64K,128K) issued after h_file  (hB dead), consumed by p-GEMV
//   WD1B-> [0,64K)  issued after s-GEMV   (Wsb dead), consumed by domain GEMV
// GEMVs become 1024-thread, 32/16-deep LDS loops (2-way bank = free).
// Output layout (f32): [0:512) logits_cls | [512:66048) h_file |
//   [66048:98816) z_shared | [98816:131584) z_private | [131584:164352) att_w
//   [164352:164864) domain_logits | [164864] ortho

typedef __attribute__((ext_vector_type(8))) short bf16x8;
typedef __attribute__((ext_vector_type(4))) short bf16x4;
typedef __attribute__((ext_vector_type(4))) float f32x4;
typedef __attribute__((ext_vector_type(8))) float f32x8;

__device__ __forceinline__ unsigned short f2bf(float f) {
  union { float f; unsigned int i; } v; v.f = f;
  unsigned int r = v.i + 0x7FFFu + ((v.i >> 16) & 1u);
  return (unsigned short)(r >> 16);
}
__device__ __forceinline__ float bf2f(unsigned short u) {
  union { unsigned int i; float f; } v; v.i = ((unsigned int)u) << 16; return v.f;
}
__device__ __forceinline__ float cvt4dot(bf16x4 v, f32x4* o) {
  (*o)[0] = bf2f(((unsigned short*)&v)[0]); (*o)[1] = bf2f(((unsigned short*)&v)[1]);
  (*o)[2] = bf2f(((unsigned short*)&v)[2]); (*o)[3] = bf2f(((unsigned short*)&v)[3]);
  return 0.f;
}
__device__ __forceinline__ int degf(int p) {  // degree+1 (self-loop)
  return 5 - (p < 2 ? 2 - p : 0) - (p > 125 ? p - 125 : 0);
}
__device__ __forceinline__ float wsum(float v) {
#pragma unroll
  for (int o = 1; o < 64; o <<= 1) v += __shfl_xor(v, o);
  return v;
}

// ---- prep: cvt-transpose W1/W2 (tiled) + flat bf16 cvt of Ws/Wp/Wd1 ------
__global__ void prep_weights(const float* __restrict__ W1, const float* __restrict__ W2,
                             const float* __restrict__ Ws, const float* __restrict__ Wp,
                             const float* __restrict__ Wd1,
                             unsigned short* __restrict__ W1t, unsigned short* __restrict__ W2t,
                             unsigned short* __restrict__ WsbG, unsigned short* __restrict__ WpbG,
                             unsigned short* __restrict__ Wd1bG) {
  __shared__ float tile[32][33];
  int id = blockIdx.x;
  int tx = threadIdx.x, ty = threadIdx.y;  // 32 x 8
  if (id >= 256) {  // flat converts: 1024 f32 per block (256 thr x f32x4)
    int id2 = id - 256;
    const float* src; unsigned short* dst; int blk;
    if (id2 < 32)      { src = Ws;  dst = WsbG;  blk = id2; }
    else if (id2 < 64) { src = Wp;  dst = WpbG;  blk = id2 - 32; }
    else               { src = Wd1; dst = Wd1bG; blk = id2 - 64; }
    int tid = ty * 32 + tx;
    int e0 = blk * 1024 + tid * 4;
    f32x4 v = *(const f32x4*)&src[e0];
    unsigned short o[4];
#pragma unroll
    for (int j = 0; j < 4; ++j) o[j] = f2bf(v[j]);
    *(bf16x4*)&dst[e0] = *(bf16x4*)o;
    return;
  }
  const float* src; unsigned short* dst; int R, C, bx, by;
  if (id < 192) { src = W1; dst = W1t; R = 768; C = 256; bx = (id % 8) * 32; by = (id / 8) * 32; }
  else { id -= 192; src = W2; dst = W2t; R = 256; C = 256; bx = (id % 8) * 32; by = (id / 8) * 32; }
#pragma unroll
  for (int j = 0; j < 32; j += 8)
    tile[ty + j][tx] = src[(by + ty + j) * C + bx + tx];
  __syncthreads();
#pragma unroll
  for (int j = 0; j < 32; j += 8)
    dst[(bx + ty + j) * R + by + tx] = f2bf(tile[tx][ty + j]);
}

// --------------------------- megakernel -----------------------------------
__global__ __launch_bounds__(1024) void mega(const float* __restrict__ A,
    const unsigned short* __restrict__ W1t, const float* __restrict__ b1,
    const unsigned short* __restrict__ W2t, const float* __restrict__ b2,
    const float* __restrict__ attn_w, const float* __restrict__ attn_b,
    const unsigned short* __restrict__ WsbG, const float* __restrict__ bs,
    const unsigned short* __restrict__ WpbG, const float* __restrict__ bp,
    const float* __restrict__ cls_w, const int* __restrict__ labels,
    const unsigned short* __restrict__ Wd1bG, const float* __restrict__ bd1,
    const float* __restrict__ Wd2, const float* __restrict__ bd2,
    float* __restrict__ out) {
  __shared__ __align__(16) char lds[131072];
  // phase1 staging (round-8 layout)
  unsigned short* sA1 = (unsigned short*)lds;            // [2][128][64] bf16, 32 KB
  unsigned short* sB1 = (unsigned short*)(lds + 32768);  // [2][256][64] bf16, 64 KB
  // post-phase1 overlays
  unsigned short* H1  = (unsigned short*)lds;            // [128][256] bf16 @ [0,64K)
  unsigned short* G1L = (unsigned short*)(lds + 65536);  // [128][256] bf16 swz @ [64K,128K)
  // phase2 overlays
  unsigned short* sB2 = (unsigned short*)lds;            // [2][256][64] bf16 @ [0,64K)
  unsigned short* H2  = (unsigned short*)lds;            // [128][256] bf16 @ [0,64K)
  unsigned short* hB  = (unsigned short*)(lds + 65536);  // [128][256] bf16 @ [64K,128K)
  // head-weight overlays (after H2/hB die)
  unsigned short* Wlo = (unsigned short*)lds;            // 64 KB @ [0,64K):  Wsb then Wd1b
  unsigned short* Whi = (unsigned short*)(lds + 65536);  // 64 KB @ [64K,128K): Wpb
  __shared__ float awS[256];
  __shared__ float lgS[128];
  __shared__ float redM[64];
  __shared__ float scr[1024];
  __shared__ float hfS[256];
  __shared__ float zsS[128], znS[128];
  __shared__ float redS[16];

  const int t = threadIdx.x;
  const int wave = t >> 6, lane = t & 63;
  const int wr = wave >> 2, wc = wave & 3;              // 4x4 waves, 32x64 tiles
  const int file = blockIdx.x;
  const long rowA = (long)file * 128;

  if (t < 256) awS[t] = attn_w[t];

  f32x4 acc[2][4];
#pragma unroll
  for (int m = 0; m < 2; ++m)
#pragma unroll
    for (int n = 0; n < 4; ++n) acc[m][n] = (f32x4)0.0f;

  // ======================= phase 1: H1 = A @ W1t^T (round-8 loop) =========
  const int arow = t >> 3, acol = (t & 7) * 8;
  const int aswz = arow * 64 + (acol ^ ((arow & 7) << 3));
  f32x8 areg;
#define ISSUE_A1(kt) areg = *(const f32x8*)&A[(rowA + arow) * 768 + (kt) * 64 + acol]
#define WRITE_A1(buf) { unsigned short u[8];                                      \
    _Pragma("unroll") for (int j = 0; j < 8; ++j) u[j] = f2bf(areg[j]);           \
    *(bf16x8*)&sA1[(buf) * 8192 + aswz] = *(bf16x8*)u; }
#define ISSUE_B1(kt, buf) _Pragma("unroll") for (int it = 0; it < 2; ++it) {      \
    int flat = (it * 1024 + t) * 8;                                               \
    int n = flat >> 6, k = flat & 63;                                             \
    const unsigned short* g = W1t + n * 768 + (kt) * 64 + (k ^ ((n & 7) << 3));   \
    __builtin_amdgcn_global_load_lds(                                             \
        (const __attribute__((address_space(1))) unsigned int*)g,                 \
        (__attribute__((address_space(3))) unsigned int*)                         \
            &sB1[(buf) * 16384 + (it * 16 + wave) * 512], 16, 0, 0); }

  ISSUE_A1(0); ISSUE_B1(0, 0); WRITE_A1(0);
  __syncthreads();
  for (int kt = 0; kt < 12; ++kt) {
    const int cur = kt & 1, nxt = cur ^ 1;
    if (kt + 1 < 12) { ISSUE_A1(kt + 1); ISSUE_B1(kt + 1, nxt); }
#pragma unroll
    for (int kk = 0; kk < 2; ++kk) {
      const int kb = kk * 32 + (lane >> 4) * 8;
      bf16x8 af[2], bfr[4];
#pragma unroll
      for (int m = 0; m < 2; ++m) {
        int r = wr * 32 + m * 16 + (lane & 15);
        af[m] = *(const bf16x8*)&sA1[cur * 8192 + r * 64 + (kb ^ ((r & 7) << 3))];
      }
#pragma unroll
      for (int n = 0; n < 4; ++n) {
        int r = wc * 64 + n * 16 + (lane & 15);
        bfr[n] = *(const bf16x8*)&sB1[cur * 16384 + r * 64 + (kb ^ ((r & 7) << 3))];
      }
#pragma unroll
      for (int m = 0; m < 2; ++m)
#pragma unroll
        for (int n = 0; n < 4; ++n)
          acc[m][n] = __builtin_amdgcn_mfma_f32_16x16x32_bf16(af[m], bfr[n], acc[m][n], 0, 0, 0);
    }
    if (kt + 1 < 12) WRITE_A1(nxt);
    __syncthreads();
  }
  // acc -> H1 (bf16).  C/D layout: col = lane&15, row = (lane>>4)*4+j
#pragma unroll
  for (int m = 0; m < 2; ++m)
#pragma unroll
    for (int n = 0; n < 4; ++n) {
      int r = wr * 32 + m * 16 + (lane >> 4) * 4;
      int c = wc * 64 + n * 16 + (lane & 15);
#pragma unroll
      for (int j = 0; j < 4; ++j) H1[(r + j) * 256 + c] = f2bf(acc[m][n][j]);
    }
  __syncthreads();
  // stencil1 + b1 + relu -> G1L (swizzled cols); it<8 covers ALL 128 lines
#pragma unroll
  for (int it = 0; it < 8; ++it) {
    int g = it * 1024 + t;
    int l = g >> 6, c0 = (g & 63) * 4;
    int dl = degf(l);
    f32x4 s = (f32x4)0.0f;
#pragma unroll
    for (int o = -2; o <= 2; ++o) {
      int q = l + o;
      if (q < 0 || q > 127) continue;
      float w = __frsqrt_rn((float)(dl * degf(q)));
      bf16x4 hv4 = *(const bf16x4*)&H1[q * 256 + c0];
      f32x4 hv; cvt4dot(hv4, &hv);
      s += w * hv;
    }
    f32x4 b = *(const f32x4*)&b1[c0];
    unsigned short o4[4];
#pragma unroll
    for (int j = 0; j < 4; ++j) o4[j] = f2bf(fmaxf(s[j] + b[j], 0.f));
    *(bf16x4*)&G1L[l * 256 + (c0 ^ ((l & 7) << 3))] = *(bf16x4*)o4;
  }
  __syncthreads();

  // ======================= phase 2: H2 = G1 @ W2t^T ========================
#pragma unroll
  for (int m = 0; m < 2; ++m)
#pragma unroll
    for (int n = 0; n < 4; ++n) acc[m][n] = (f32x4)0.0f;
#define ISSUE_B2(kt, buf) _Pragma("unroll") for (int it = 0; it < 2; ++it) {      \
    int flat = (it * 1024 + t) * 8;                                               \
    int n = flat >> 6, k = flat & 63;                                             \
    const unsigned short* g = W2t + n * 256 + (kt) * 64 + (k ^ ((n & 7) << 3));   \
    __builtin_amdgcn_global_load_lds(                                             \
        (const __attribute__((address_space(1))) unsigned int*)g,                 \
        (__attribute__((address_space(3))) unsigned int*)                         \
            &sB2[(buf) * 16384 + (it * 16 + wave) * 512], 16, 0, 0); }

  ISSUE_B2(0, 0);
  __syncthreads();
  for (int kt = 0; kt < 4; ++kt) {
    const int cur = kt & 1, nxt = cur ^ 1;
    if (kt + 1 < 4) ISSUE_B2(kt + 1, nxt);
#pragma unroll
    for (int kk = 0; kk < 2; ++kk) {
      const int kb = kk * 32 + (lane >> 4) * 8;
      bf16x8 af[2], bfr[4];
#pragma unroll
      for (int m = 0; m < 2; ++m) {
        int r = wr * 32 + m * 16 + (lane & 15);
        int col = kt * 64 + kb;
        af[m] = *(const bf16x8*)&G1L[r * 256 + (col ^ ((r & 7) << 3))];
      }
#pragma unroll
      for (int n = 0; n < 4; ++n) {
        int r = wc * 64 + n * 16 + (lane & 15);
        bfr[n] = *(const bf16x8*)&sB2[cur * 16384 + r * 64 + (kb ^ ((r & 7) << 3))];
      }
#pragma unroll
      for (int m = 0; m < 2; ++m)
#pragma unroll
        for (int n = 0; n < 4; ++n)
          acc[m][n] = __builtin_amdgcn_mfma_f32_16x16x32_bf16(af[m], bfr[n], acc[m][n], 0, 0, 0);
    }
    __syncthreads();
  }
  // acc -> H2 (bf16, over dead sB2)
#pragma unroll
  for (int m = 0; m < 2; ++m)
#pragma unroll
    for (int n = 0; n < 4; ++n) {
      int r = wr * 32 + m * 16 + (lane >> 4) * 4;
      int c = wc * 64 + n * 16 + (lane & 15);
#pragma unroll
      for (int j = 0; j < 4; ++j) H2[(r + j) * 256 + c] = f2bf(acc[m][n][j]);
    }
  __syncthreads();
  // stencil2 + b2 -> hB (over dead G1L); it<8 covers ALL 128 lines
#pragma unroll
  for (int it = 0; it < 8; ++it) {
    int g = it * 1024 + t;
    int l = g >> 6, c0 = (g & 63) * 4;
    int dl = degf(l);
    f32x4 s = (f32x4)0.0f;
#pragma unroll
    for (int o = -2; o <= 2; ++o) {
      int q = l + o;
      if (q < 0 || q > 127) continue;
      float w = __frsqrt_rn((float)(dl * degf(q)));
      bf16x4 hv4 = *(const bf16x4*)&H2[q * 256 + c0];
      f32x4 hv; cvt4dot(hv4, &hv);
      s += w * hv;
    }
    f32x4 b = *(const f32x4*)&b2[c0];
    unsigned short o4[4];
#pragma unroll
    for (int j = 0; j < 4; ++j) o4[j] = f2bf(s[j] + b[j]);
    *(bf16x4*)&hB[l * 256 + c0] = *(bf16x4*)o4;
  }
  __syncthreads();
  // H2 region [0,64K) now dead -> stage Wsb (bf16 [256][128], 64 KB) there.
#define ISSUE_WB(srcG, dstL, rounds) _Pragma("unroll") for (int it = 0; it < (rounds); ++it) { \
    const unsigned short* g = (srcG) + (it * 1024 + t) * 8;                        \
    __builtin_amdgcn_global_load_lds(                                              \
        (const __attribute__((address_space(1))) unsigned int*)g,                  \
        (__attribute__((address_space(3))) unsigned int*)                          \
            &(dstL)[(it * 16 + wave) * 512], 16, 0, 0); }
  ISSUE_WB(WsbG, Wlo, 4);

  // ======================= attention pooling (reads hB) ====================
  {  // logits: 8 lanes per line, rotated channel order
    int l = t >> 3, p = t & 7;
    float part = 0.f;
#pragma unroll 4
    for (int j = 0; j < 32; ++j) {
      int c = p * 32 + ((j + 4 * p + l) & 31);
      part += bf2f(hB[l * 256 + c]) * awS[c];
    }
    part += __shfl_xor(part, 1);
    part += __shfl_xor(part, 2);
    part += __shfl_xor(part, 4);
    if (p == 0) lgS[l] = part + attn_b[0];
  }
  __syncthreads();
  if (t < 64) redM[t] = fmaxf(lgS[t], lgS[t + 64]);
  __syncthreads();
  for (int s = 32; s > 0; s >>= 1) {
    if (t < s) redM[t] = fmaxf(redM[t], redM[t + s]);
    __syncthreads();
  }
  float mx = redM[0];
  __syncthreads();
  if (t < 128) lgS[t] = expf(lgS[t] - mx);
  __syncthreads();
  if (t < 64) redM[t] = lgS[t] + lgS[t + 64];
  __syncthreads();
  for (int s = 32; s > 0; s >>= 1) {
    if (t < s) redM[t] += redM[t + s];
    __syncthreads();
  }
  float dn = redM[0];
  __syncthreads();
  if (t < 128) {
    float w = lgS[t] / dn;
    lgS[t] = w;
    out[131584 + file * 128 + t] = w;
  }
  __syncthreads();
  {  // h_file partials
    int c = t & 255, grp = t >> 8;
    float s = 0.f;
    for (int l = grp * 32; l < grp * 32 + 32; ++l) s += lgS[l] * bf2f(hB[l * 256 + c]);
    scr[grp * 256 + c] = s;
  }
  __syncthreads();
  if (t < 256) {
    float tot = scr[t] + scr[256 + t] + scr[512 + t] + scr[768 + t];
    hfS[t] = tot;
    out[512 + file * 256 + t] = tot;
  }
  __syncthreads();   // hB dead from here; Wsb landed (barrier drains vmcnt)

  // ======================= heads (LDS-staged bf16 weights) =================
  ISSUE_WB(WpbG, Whi, 4);   // stage Wpb into dead hB region during s-GEMV
  {  // s-GEMV: 8 c-groups x 128 j, 32-deep, Wsb from LDS
    int g = t >> 7, j = t & 127;
    float s = 0.f;
#pragma unroll 8
    for (int c = g * 32; c < g * 32 + 32; ++c) s += hfS[c] * bf2f(Wlo[c * 128 + j]);
    scr[g * 128 + j] = s;
  }
  __syncthreads();   // Wsb reads done; Wpb landed
  ISSUE_WB(Wd1bG, Wlo, 2);  // stage Wd1b over dead Wsb during z_s combine
  if (t < 128) {
    float zs = bs[t];
#pragma unroll
    for (int g = 0; g < 8; ++g) zs += scr[g * 128 + t];
    zsS[t] = zs;
    out[66048 + file * 128 + t] = zs;
    float s = wsum(zs * zs);
    if (lane == 0) redS[wave] = s;            // waves 0,1
  }
  __syncthreads();
  if (t == 0) redS[8] = fmaxf(sqrtf(redS[0] + redS[1]), 1e-12f);
  {  // p-GEMV: Wpb from LDS
    int g = t >> 7, j = t & 127;
    float s = 0.f;
#pragma unroll 8
    for (int c = g * 32; c < g * 32 + 32; ++c) s += hfS[c] * bf2f(Whi[c * 128 + j]);
    scr[g * 128 + j] = s;
  }
  __syncthreads();
  if (t < 128) {
    znS[t] = zsS[t] / redS[8];
  } else if (t < 256) {
    int j = t - 128;
    float zp = bp[j];
#pragma unroll
    for (int g = 0; g < 8; ++g) zp += scr[g * 128 + j];
    out[98816 + file * 128 + j] = zp;
  }
  __syncthreads();
  {  // AM-softmax: dot(zsn, cls_w[:,k]) and ||cls_w[:,k]||
    int j = t & 127;
    if (t < 512) {
      float v;
      if (t < 128)       v = znS[j] * cls_w[j * 2 + 0];
      else if (t < 256)  v = znS[j] * cls_w[j * 2 + 1];
      else if (t < 384)  { float w0 = cls_w[j * 2 + 0]; v = w0 * w0; }
      else               { float w1 = cls_w[j * 2 + 1]; v = w1 * w1; }
      float s = wsum(v);
      if (lane == 0) redS[wave] = s;           // waves 0..7
    }
  }
  __syncthreads();
  if (t == 0) {
    float d0 = redS[0] + redS[1], d1 = redS[2] + redS[3];
    float n0 = fmaxf(sqrtf(redS[4] + redS[5]), 1e-12f);
    float n1 = fmaxf(sqrtf(redS[6] + redS[7]), 1e-12f);
    int lab = labels[file];
    out[file * 2 + 0] = 30.0f * (d0 / n0 - 0.35f * (lab == 0 ? 1.f : 0.f));
    out[file * 2 + 1] = 30.0f * (d1 / n1 - 0.35f * (lab == 1 ? 1.f : 0.f));
  }
  __syncthreads();
  {  // domain GEMV: Wd1b [128][128] bf16 from LDS, 8 groups x 16-deep
    int g = t >> 7, j = t & 127;
    float s = 0.f;
#pragma unroll 8
    for (int a = g * 16; a < g * 16 + 16; ++a) s += zsS[a] * bf2f(Wlo[a * 128 + j]);
    scr[g * 128 + j] = s;
  }
  __syncthreads();
  if (t < 128) {
    float dd = bd1[t];
#pragma unroll
    for (int g = 0; g < 8; ++g) dd += scr[g * 128 + t];
    dd = fmaxf(dd, 0.f);
    float s0 = wsum(dd * Wd2[t * 2 + 0]);
    if (lane == 0) redS[wave] = s0;           // waves 0,1
    float s1 = wsum(dd * Wd2[t * 2 + 1]);
    if (lane == 0) redS[4 + wave] = s1;
  }
  __syncthreads();
  if (t == 0) {
    out[164352 + file * 2 + 0] = redS[0] + redS[1] + bd2[0];
    out[164352 + file * 2 + 1] = redS[4] + redS[5] + bd2[1];
  }
#undef ISSUE_A1
#undef WRITE_A1
#undef ISSUE_B1
#undef ISSUE_B2
#undef ISSUE_WB
}

// ------- znorm: zsn/zpn from validated z_shared/z_private in d_out --------
__global__ __launch_bounds__(128) void znorm(const float* __restrict__ out,
                                             float* __restrict__ zsn,
                                             float* __restrict__ zpn) {
  const int f = blockIdx.x, j = threadIdx.x;
  __shared__ float red[128];
  float zs = out[66048 + f * 128 + j];
  float zp = out[98816 + f * 128 + j];
  red[j] = zs * zs; __syncthreads();
  for (int s = 64; s > 0; s >>= 1) { if (j < s) red[j] += red[j + s]; __syncthreads(); }
  float ns = sqrtf(red[0]); __syncthreads();
  zsn[f * 128 + j] = zs / fmaxf(ns, 1e-12f);
  red[j] = zp * zp; __syncthreads();
  for (int s = 64; s > 0; s >>= 1) { if (j < s) red[j] += red[j + s]; __syncthreads(); }
  float np = sqrtf(red[0]); __syncthreads();
  zpn[f * 128 + j] = zp / fmaxf(np, 1e-12f);
}

// ---------------- ortho: ||zsn^T @ zpn||_F --------------------------------
__global__ __launch_bounds__(128) void ortho_partial(const float* __restrict__ zsn,
                                                     const float* __restrict__ zpn,
                                                     float* __restrict__ partial) {
  const int a = blockIdx.x, b = threadIdx.x;
  float s = 0.f;
  for (int f = 0; f < 256; ++f) s += zsn[f * 128 + a] * zpn[f * 128 + b];
  __shared__ float red[128];
  red[b] = s * s; __syncthreads();
  for (int st = 64; st > 0; st >>= 1) { if (b < st) red[b] += red[b + st]; __syncthreads(); }
  if (b == 0) partial[a] = red[0];
}

__global__ __launch_bounds__(128) void ortho_final(const float* __restrict__ partial,
                                                   float* __restrict__ out) {
  const int t = threadIdx.x;
  __shared__ float red[128];
  red[t] = partial[t]; __syncthreads();
  for (int st = 64; st > 0; st >>= 1) { if (t < st) red[t] += red[t + st]; __syncthreads(); }
  if (t == 0) out[164864] = sqrtf(red[0]);
}

extern "C" void kernel_launch(void* const* d_in, const int* in_sizes, int n_in,
                              void* d_out, int out_size, void* d_ws, size_t ws_size,
                              hipStream_t stream) {
  const float* line_emb = (const float*)d_in[0];
  const float* W1     = (const float*)d_in[1];
  const float* b1     = (const float*)d_in[2];
  const float* W2     = (const float*)d_in[3];
  const float* b2     = (const float*)d_in[4];
  const float* attn_w = (const float*)d_in[5];
  const float* attn_b = (const float*)d_in[6];
  const float* Ws     = (const float*)d_in[7];
  const float* bs     = (const float*)d_in[8];
  const float* Wp     = (const float*)d_in[9];
  const float* bp     = (const float*)d_in[10];
  const float* cls_w  = (const float*)d_in[11];
  const float* Wd1    = (const float*)d_in[12];
  const float* bd1    = (const float*)d_in[13];
  const float* Wd2    = (const float*)d_in[14];
  const float* bd2    = (const float*)d_in[15];
  const int* labels   = (const int*)d_in[18];

  char* ws = (char*)d_ws;
  unsigned short* W1t  = (unsigned short*)(ws + 0);        // [256][768] bf16
  unsigned short* W2t  = (unsigned short*)(ws + 393216);   // [256][256] bf16
  float* zsn           = (float*)(ws + 524288);            // [256][128] f32
  float* zpn           = (float*)(ws + 655360);            // [256][128] f32
  float* partial       = (float*)(ws + 786432);            // 128 f32
  unsigned short* WsbG = (unsigned short*)(ws + 1048576);  // [256][128] bf16, 64 KB
  unsigned short* WpbG = (unsigned short*)(ws + 1114112);  // [256][128] bf16, 64 KB
  unsigned short* Wd1bG= (unsigned short*)(ws + 1179648);  // [128][128] bf16, 32 KB
  float* out           = (float*)d_out;

  prep_weights<<<dim3(336), dim3(32, 8), 0, stream>>>(W1, W2, Ws, Wp, Wd1,
                                                      W1t, W2t, WsbG, WpbG, Wd1bG);
  mega<<<dim3(256), dim3(1024), 0, stream>>>(line_emb, W1t, b1, W2t, b2,
                                             attn_w, attn_b, WsbG, bs, WpbG, bp,
                                             cls_w, labels, Wd1bG, bd1, Wd2, bd2, out);
  znorm<<<dim3(256), dim3(128), 0, stream>>>(out, zsn, zpn);
  ortho_partial<<<dim3(128), dim3(128), 0, stream>>>(zsn, zpn, partial);
  ortho_final<<<dim3(1), dim3(128), 0, stream>>>(partial, out);
}